// Round 1
// baseline (627.333 us; speedup 1.0000x reference)
//
#include <hip/hip_runtime.h>
#include <hip/hip_bf16.h>
#include <math.h>

typedef float f32x4 __attribute__((ext_vector_type(4)));
typedef short s16x8 __attribute__((ext_vector_type(8)));
typedef short s16x4 __attribute__((ext_vector_type(4)));
typedef unsigned int u32;

#define DEVI __device__ __forceinline__

// ---- sizes ----
#define Bn   8
#define Sn   512
#define Hn   1024
#define Tn   8
#define Kn   2
#define FFn  4096
#define NHn  8
#define HDn  128
#define Ln   1024            // K*S
#define OUT_COMBINED 4194304 // B*S*H

DEVI unsigned short f2bf(float x) {
  __hip_bfloat16 h = __float2bfloat16(x);
  union { __hip_bfloat16 h; unsigned short u; } cv; cv.h = h; return cv.u;
}
DEVI float bf2f(unsigned short u) {
  union { u32 i; float f; } cv; cv.i = ((u32)u) << 16; return cv.f;
}

typedef __attribute__((address_space(3))) u32 lds_u32;
typedef __attribute__((address_space(1))) u32 glb_u32;
DEVI void gload16(const void* g, void* l) {
  __builtin_amdgcn_global_load_lds((const glb_u32*)g, (lds_u32*)l, 16, 0, 0);
}

// ---------------- pool (mean over S) ----------------
__global__ __launch_bounds__(256) void pool_part_k(const float* __restrict__ hid, float* __restrict__ part)
{
  const int b = blockIdx.x, scn = blockIdx.y;
  const int hh = threadIdx.x * 4;
  float4 acc = make_float4(0.f, 0.f, 0.f, 0.f);
  const float* base = hid + ((long)b * Sn + (long)scn * 128) * Hn + hh;
  for (int s = 0; s < 128; ++s) {
    float4 v = *(const float4*)(base + (long)s * Hn);
    acc.x += v.x; acc.y += v.y; acc.z += v.z; acc.w += v.w;
  }
  *(float4*)(part + ((long)(scn * Bn + b)) * Hn + hh) = acc;
}

__global__ __launch_bounds__(256) void pool_final_k(const float* __restrict__ part, float* __restrict__ pooled)
{
  const int i = blockIdx.x * 256 + threadIdx.x;
  float s = 0.f;
  for (int sc = 0; sc < 4; ++sc) s += part[sc * (Bn * Hn) + i];
  pooled[i] = s * (1.f / (float)Sn);
}

// ---------------- router + entropy ----------------
__global__ __launch_bounds__(64) void router_k(
    const float* __restrict__ pooled, const float* __restrict__ rw, const float* __restrict__ rb,
    float* __restrict__ probs, int* __restrict__ topi, float* __restrict__ wts,
    int* __restrict__ flags, float* __restrict__ entropy_out)
{
  __shared__ float lg[64];
  __shared__ int sfl[8];
  __shared__ float sent[8];
  const int tid = threadIdx.x;
  const int b = tid >> 3, t = tid & 7;
  if (tid < 8) sfl[tid] = 0;
  float acc = rb[t];
  const float* pb = pooled + b * Hn;
  for (int i = 0; i < Hn; ++i) acc += pb[i] * rw[i * Tn + t];
  lg[tid] = acc;
  __syncthreads();
  if (t == 0) {
    float p[8];
    float mx = lg[b * 8];
    for (int i = 1; i < 8; ++i) mx = fmaxf(mx, lg[b * 8 + i]);
    float ssum = 0.f;
    for (int i = 0; i < 8; ++i) { p[i] = expf(lg[b * 8 + i] - mx); ssum += p[i]; }
    float ent = 0.f;
    for (int i = 0; i < 8; ++i) { p[i] /= ssum; ent -= p[i] * logf(p[i] + 1e-8f); probs[b * 8 + i] = p[i]; }
    sent[b] = ent;
    int i1 = 0;
    for (int i = 1; i < 8; ++i) if (p[i] > p[i1]) i1 = i;   // strict > : lowest index on ties (lax.top_k)
    int i2 = (i1 == 0) ? 1 : 0;
    for (int i = 0; i < 8; ++i) if (i != i1 && p[i] > p[i2]) i2 = i;
    // weights = softmax over the two top PROBS (reference applies softmax to top_p)
    float w0 = 1.f / (1.f + expf(p[i2] - p[i1]));
    float w1 = 1.f / (1.f + expf(p[i1] - p[i2]));
    topi[b * 2] = i1; topi[b * 2 + 1] = i2;
    wts[b * 2] = w0; wts[b * 2 + 1] = w1;
    atomicOr(&sfl[i1], 1); atomicOr(&sfl[i2], 1);
  }
  __syncthreads();
  if (tid < 8) flags[tid] = sfl[tid];
  if (tid == 0) {
    float e = 0.f;
    for (int i = 0; i < 8; ++i) e += sent[i];
    entropy_out[0] = e * (1.f / (float)Bn);
  }
}

// ---------------- f32 -> bf16 convert ----------------
__global__ __launch_bounds__(256) void cvt_k(const float* __restrict__ in, unsigned short* __restrict__ out)
{
  const long i = ((long)blockIdx.x * 256 + threadIdx.x) * 4;
  float4 v = *(const float4*)(in + i);
  s16x4 o;
  o[0] = (short)f2bf(v.x); o[1] = (short)f2bf(v.y); o[2] = (short)f2bf(v.z); o[3] = (short)f2bf(v.w);
  *(s16x4*)(out + i) = o;
}

// ---------------- transpose+convert: in f32 [Kd][N] -> out bf16 [N][Kd] ----------------
__global__ __launch_bounds__(256) void transpose_k(const float* __restrict__ Win, unsigned short* __restrict__ Wout,
                                                   int Kd, int N, long sIn, long sOut, const int* __restrict__ flags)
{
  const int t = blockIdx.z;
  if (flags && flags[t] == 0) return;   // uniform per block
  __shared__ float tile[32][33];
  const float* in = Win + (long)t * sIn;
  unsigned short* out = Wout + (long)t * sOut;
  const int kb = blockIdx.y * 32, nb = blockIdx.x * 32;
  const int tx = threadIdx.x & 31, ty = threadIdx.x >> 5;
  #pragma unroll
  for (int i = 0; i < 4; ++i) {
    const int r = ty + i * 8;
    tile[r][tx] = in[(long)(kb + r) * N + nb + tx];
  }
  __syncthreads();
  #pragma unroll
  for (int i = 0; i < 4; ++i) {
    const int r = ty + i * 8;
    out[(long)(nb + r) * Kd + kb + tx] = f2bf(tile[tx][r]);
  }
}

// ---------------- GEMM: C[M,N](bf16) = A[M,Kd](bf16) @ Bt[N,Kd]^T (bf16) + bias ----------------
// EPI: 0 none, 1 exact gelu.  OUTMODE: 0 normal [M][N]; 1 V-transposed -> vt[(b*1024+n)][ltok]
template<int EPI, int OUTMODE>
__global__ __launch_bounds__(256) void gemm_k(
    const unsigned short* __restrict__ A0, const unsigned short* __restrict__ Bt0,
    const float* __restrict__ bias0, unsigned short* __restrict__ C0,
    int N, int Kd,
    const int* __restrict__ topi, int kTop,
    long sA_b, long sA_p, long sBt_t, int sBias_t, long sC_p)
{
  __shared__ unsigned short As[128 * 32];
  __shared__ unsigned short Bs[128 * 32];
  const int z = blockIdx.z;
  const int bidx = kTop ? (z / kTop) : 0;
  const int t = topi ? topi[z] : 0;
  const unsigned short* A = A0 + (long)bidx * sA_b + (long)z * sA_p;
  const unsigned short* Bt = Bt0 + (long)t * sBt_t;
  const float* bias = bias0 + (long)t * sBias_t;
  unsigned short* C = C0 + (long)z * sC_p;

  const int m0 = blockIdx.y * 128;
  const int n0 = blockIdx.x * 128;
  const int tid = threadIdx.x;
  const int lane = tid & 63, w = tid >> 6;
  const int wm = w >> 1, wn = w & 1;

  // staging: wave w owns rows [w*32, w*32+32) of both tiles; 2 issues of 16B/lane each.
  // LDS layout linear [row][32 bf16]; XOR swizzle c ^= (row^(row>>2))&3 applied by
  // pre-swizzling the GLOBAL chunk (global_load_lds dest must stay linear).
  const int srow = w * 32 + (lane >> 2);
  const int csw = ((lane & 3) ^ ((srow ^ (srow >> 2)) & 3)) << 4;

  const char* gA0 = (const char*)(A + (long)(m0 + srow) * Kd) + csw;
  const char* gA1 = (const char*)(A + (long)(m0 + srow + 16) * Kd) + csw;
  const char* gB0 = (const char*)(Bt + (long)(n0 + srow) * Kd) + csw;
  const char* gB1 = (const char*)(Bt + (long)(n0 + srow + 16) * Kd) + csw;

  char* ldsA = (char*)As + w * 2048;
  char* ldsB = (char*)Bs + w * 2048;

  f32x4 acc[4][4];
  const f32x4 zero = {0.f, 0.f, 0.f, 0.f};
  #pragma unroll
  for (int i = 0; i < 4; ++i)
    #pragma unroll
    for (int j = 0; j < 4; ++j) acc[i][j] = zero;

  const int rA = lane & 15;
  const int cb = (lane >> 4) << 4;
  int aoff[4], boff[4];
  #pragma unroll
  for (int mi = 0; mi < 4; ++mi) {
    int row = wm * 64 + mi * 16 + rA;
    aoff[mi] = row * 64 + (cb ^ (((row ^ (row >> 2)) & 3) << 4));
    int rowb = wn * 64 + mi * 16 + rA;
    boff[mi] = rowb * 64 + (cb ^ (((rowb ^ (rowb >> 2)) & 3) << 4));
  }

  const int nIter = Kd >> 5;
  for (int it = 0; it < nIter; ++it) {
    const long kbyte = (long)it * 64;
    __syncthreads();
    gload16(gA0 + kbyte, ldsA);
    gload16(gA1 + kbyte, ldsA + 1024);
    gload16(gB0 + kbyte, ldsB);
    gload16(gB1 + kbyte, ldsB + 1024);
    __syncthreads();
    s16x8 af[4], bfr[4];
    #pragma unroll
    for (int mi = 0; mi < 4; ++mi) af[mi] = *(const s16x8*)((const char*)As + aoff[mi]);
    #pragma unroll
    for (int nj = 0; nj < 4; ++nj) bfr[nj] = *(const s16x8*)((const char*)Bs + boff[nj]);
    #pragma unroll
    for (int mi = 0; mi < 4; ++mi)
      #pragma unroll
      for (int nj = 0; nj < 4; ++nj)
        acc[mi][nj] = __builtin_amdgcn_mfma_f32_16x16x32_bf16(af[mi], bfr[nj], acc[mi][nj], 0, 0, 0);
  }

  const int r4 = (lane >> 4) << 2;
  #pragma unroll
  for (int nj = 0; nj < 4; ++nj) {
    const int n = n0 + wn * 64 + nj * 16 + rA;
    const float bv = bias[n];
    #pragma unroll
    for (int mi = 0; mi < 4; ++mi) {
      const int mrow = m0 + wm * 64 + mi * 16 + r4;
      if (OUTMODE == 0) {
        #pragma unroll
        for (int j = 0; j < 4; ++j) {
          float x = acc[mi][nj][j] + bv;
          if (EPI == 1) x = 0.5f * x * (1.0f + erff(x * 0.70710678118654752f));
          C[(long)(mrow + j) * N + n] = f2bf(x);
        }
      } else {
        const int bb = mrow >> 10;       // M rows per batch = L = 1024
        const int ltok = mrow & 1023;
        s16x4 pk;
        #pragma unroll
        for (int j = 0; j < 4; ++j) pk[j] = (short)f2bf(acc[mi][nj][j] + bv);
        *(s16x4*)(C + ((long)(bb * 1024 + n)) * 1024 + ltok) = pk;
      }
    }
  }
}

// ---------------- flash attention ----------------
// q,k: [B*L][H] bf16 ; vt: [B*NH*HD][L] bf16 ; ctx: [B*L][H] bf16
__global__ __launch_bounds__(256) void flash_k(
    const unsigned short* __restrict__ q, const unsigned short* __restrict__ k,
    const unsigned short* __restrict__ vt, unsigned short* __restrict__ ctx)
{
  __shared__ unsigned short Ks[64 * 128];   // [kv][hd], rows 256B, chunk^=(row&7)
  __shared__ unsigned short Vs[128 * 64];   // [hd][kv], rows 128B, chunk^=(row&7)
  __shared__ unsigned short Ps[4][16 * 72]; // per-wave P, pitch 72 bf16 (144B)
  const int qt = blockIdx.x, h = blockIdx.y, b = blockIdx.z;
  const int tid = threadIdx.x, lane = tid & 63, w = tid >> 6;
  const int q0 = qt * 64;
  const int rA = lane & 15;

  const int qrow = q0 + w * 16 + rA;
  const unsigned short* qp = q + ((long)(b * Ln + qrow)) * Hn + h * HDn + ((lane >> 4) * 8);
  s16x8 qf[4];
  #pragma unroll
  for (int kk = 0; kk < 4; ++kk) qf[kk] = *(const s16x8*)(qp + kk * 32);

  f32x4 o[8];
  const f32x4 zero = {0.f, 0.f, 0.f, 0.f};
  #pragma unroll
  for (int i = 0; i < 8; ++i) o[i] = zero;
  float mrun[4], lrun[4];
  #pragma unroll
  for (int j = 0; j < 4; ++j) { mrun[j] = -1e30f; lrun[j] = 0.f; }

  const float sc = 0.08838834764831845f * 1.4426950408889634f;  // 1/sqrt(128) * log2(e)

  const int krow0 = w * 16 + (lane >> 4);
  const int kc = lane & 15;
  const int vrow0 = w * 32 + (lane >> 3);
  const int vc = lane & 7;

  for (int kvt = 0; kvt < 16; ++kvt) {
    const int kv0 = kvt * 64;
    __syncthreads();
    #pragma unroll
    for (int qq = 0; qq < 4; ++qq) {
      const int rk = krow0 + qq * 4;
      gload16(k + ((long)(b * Ln + kv0 + rk)) * Hn + h * HDn + ((kc ^ (rk & 7)) * 8),
              (char*)Ks + w * 4096 + qq * 1024);
      const int rv = vrow0 + qq * 8;
      gload16(vt + ((long)(b * 1024 + h * HDn + rv)) * Ln + kv0 + ((vc ^ (rv & 7)) * 8),
              (char*)Vs + w * 4096 + qq * 1024);
    }
    __syncthreads();

    f32x4 sacc[4];
    #pragma unroll
    for (int nj = 0; nj < 4; ++nj) sacc[nj] = zero;
    #pragma unroll
    for (int kk = 0; kk < 4; ++kk) {
      #pragma unroll
      for (int nj = 0; nj < 4; ++nj) {
        const int row = nj * 16 + rA;
        const int byt = row * 256 + (((kk * 4 + (lane >> 4)) ^ (row & 7)) << 4);
        s16x8 kf = *(const s16x8*)((const char*)Ks + byt);
        sacc[nj] = __builtin_amdgcn_mfma_f32_16x16x32_bf16(qf[kk], kf, sacc[nj], 0, 0, 0);
      }
    }

    #pragma unroll
    for (int j = 0; j < 4; ++j) {
      float s0 = sacc[0][j] * sc, s1 = sacc[1][j] * sc, s2 = sacc[2][j] * sc, s3 = sacc[3][j] * sc;
      float tmax = fmaxf(fmaxf(s0, s1), fmaxf(s2, s3));
      #pragma unroll
      for (int mm = 1; mm < 16; mm <<= 1) tmax = fmaxf(tmax, __shfl_xor(tmax, mm, 64));
      const float mn = fmaxf(mrun[j], tmax);
      const float al = exp2f(mrun[j] - mn);
      mrun[j] = mn;
      float p0 = exp2f(s0 - mn), p1 = exp2f(s1 - mn), p2 = exp2f(s2 - mn), p3 = exp2f(s3 - mn);
      float ts = p0 + p1 + p2 + p3;
      #pragma unroll
      for (int mm = 1; mm < 16; mm <<= 1) ts += __shfl_xor(ts, mm, 64);
      lrun[j] = lrun[j] * al + ts;
      #pragma unroll
      for (int nn = 0; nn < 8; ++nn) o[nn][j] *= al;
      const int prow = ((lane >> 4) * 4 + j) * 72;
      Ps[w][prow + 0 * 16 + rA] = f2bf(p0);
      Ps[w][prow + 1 * 16 + rA] = f2bf(p1);
      Ps[w][prow + 2 * 16 + rA] = f2bf(p2);
      Ps[w][prow + 3 * 16 + rA] = f2bf(p3);
    }

    s16x8 pf[2];
    #pragma unroll
    for (int kk2 = 0; kk2 < 2; ++kk2)
      pf[kk2] = *(const s16x8*)((const char*)&Ps[w][0] + rA * 144 + kk2 * 64 + ((lane >> 4) << 4));
    #pragma unroll
    for (int kk2 = 0; kk2 < 2; ++kk2) {
      #pragma unroll
      for (int nn = 0; nn < 8; ++nn) {
        const int row = nn * 16 + rA;
        const int byt = row * 128 + (((kk2 * 4 + (lane >> 4)) ^ (row & 7)) << 4);
        s16x8 vf = *(const s16x8*)((const char*)Vs + byt);
        o[nn] = __builtin_amdgcn_mfma_f32_16x16x32_bf16(pf[kk2], vf, o[nn], 0, 0, 0);
      }
    }
  }

  #pragma unroll
  for (int nn = 0; nn < 8; ++nn) {
    #pragma unroll
    for (int j = 0; j < 4; ++j) {
      const int row = q0 + w * 16 + ((lane >> 4) << 2) + j;
      ctx[((long)(b * Ln + row)) * Hn + h * HDn + nn * 16 + rA] = f2bf(o[nn][j] / lrun[j]);
    }
  }
}

// ---------------- diversity ----------------
__global__ __launch_bounds__(256) void div_part_k(const unsigned short* __restrict__ br, float* __restrict__ part)
{
  const int b = blockIdx.y, ch = blockIdx.x;
  const unsigned short* a = br + (long)b * (2L * Sn * Hn);
  const unsigned short* c = a + (long)Sn * Hn;
  const int base = ch * 16384 + threadIdx.x * 8;
  float dot = 0.f, na = 0.f, nb = 0.f;
  #pragma unroll
  for (int i = 0; i < 8; ++i) {
    const int idx = base + i * 2048;
    s16x8 av = *(const s16x8*)(a + idx);
    s16x8 cv = *(const s16x8*)(c + idx);
    #pragma unroll
    for (int e = 0; e < 8; ++e) {
      float fa = bf2f((unsigned short)av[e]);
      float fc = bf2f((unsigned short)cv[e]);
      dot += fa * fc; na += fa * fa; nb += fc * fc;
    }
  }
  #pragma unroll
  for (int mm = 1; mm < 64; mm <<= 1) {
    dot += __shfl_xor(dot, mm, 64);
    na  += __shfl_xor(na, mm, 64);
    nb  += __shfl_xor(nb, mm, 64);
  }
  __shared__ float red[12];
  const int lane = threadIdx.x & 63, w = threadIdx.x >> 6;
  if (lane == 0) { red[w * 3] = dot; red[w * 3 + 1] = na; red[w * 3 + 2] = nb; }
  __syncthreads();
  if (threadIdx.x == 0) {
    float d = 0, x = 0, y = 0;
    for (int i = 0; i < 4; ++i) { d += red[i * 3]; x += red[i * 3 + 1]; y += red[i * 3 + 2]; }
    float* op = part + ((long)(b * 32 + ch)) * 3;
    op[0] = d; op[1] = x; op[2] = y;
  }
}

__global__ __launch_bounds__(64) void div_final_k(const float* __restrict__ part, float* __restrict__ outp)
{
  __shared__ float cosr[8];
  const int tid = threadIdx.x;
  if (tid < 8) {
    float d = 0, x = 0, y = 0;
    for (int i = 0; i < 32; ++i) {
      const float* p = part + ((long)(tid * 32 + i)) * 3;
      d += p[0]; x += p[1]; y += p[2];
    }
    cosr[tid] = d / fmaxf(sqrtf(x) * sqrtf(y), 1e-8f);
  }
  __syncthreads();
  if (tid == 0) {
    float s = 0.f;
    for (int i = 0; i < 8; ++i) s += 1.f - cosr[i];
    outp[0] = s * (1.f / 8.f);
  }
}

// ---------------- weighted combine ----------------
__global__ __launch_bounds__(256) void combine_k(const unsigned short* __restrict__ att,
                                                 const float* __restrict__ wts, float* __restrict__ out)
{
  const long i = ((long)blockIdx.x * 256 + threadIdx.x) * 8;
  const int b = (int)(i >> 19);           // S*H = 524288
  const long rem = i & 524287;
  const unsigned short* a0 = att + (long)b * (2L * Sn * Hn) + rem;
  const unsigned short* a1 = a0 + (long)Sn * Hn;
  const float w0 = wts[b * 2], w1 = wts[b * 2 + 1];
  s16x8 v0 = *(const s16x8*)a0;
  s16x8 v1 = *(const s16x8*)a1;
  float r[8];
  #pragma unroll
  for (int e = 0; e < 8; ++e) r[e] = w0 * bf2f((unsigned short)v0[e]) + w1 * bf2f((unsigned short)v1[e]);
  *(float4*)(out + i)     = make_float4(r[0], r[1], r[2], r[3]);
  *(float4*)(out + i + 4) = make_float4(r[4], r[5], r[6], r[7]);
}

// ---------------- launch ----------------
extern "C" void kernel_launch(void* const* d_in, const int* in_sizes, int n_in,
                              void* d_out, int out_size, void* d_ws, size_t ws_size,
                              hipStream_t stream)
{
  (void)in_sizes; (void)n_in; (void)out_size; (void)ws_size;
  const float* hidden   = (const float*)d_in[0];
  const float* router_w = (const float*)d_in[1];
  const float* router_b = (const float*)d_in[2];
  const float* W1 = (const float*)d_in[3];
  const float* b1 = (const float*)d_in[4];
  const float* W2 = (const float*)d_in[5];
  const float* b2 = (const float*)d_in[6];
  const float* Wq = (const float*)d_in[7];
  const float* bq = (const float*)d_in[8];
  const float* Wk = (const float*)d_in[9];
  const float* bk = (const float*)d_in[10];
  const float* Wv = (const float*)d_in[11];
  const float* bv = (const float*)d_in[12];
  const float* Wo = (const float*)d_in[13];
  const float* bo = (const float*)d_in[14];
  float* out = (float*)d_out;

  char* ws = (char*)d_ws;
  // small region (<256KB)
  float* pooled = (float*)(ws);                    // 32KB
  float* ppart  = (float*)(ws + 32768);            // 128KB
  float* probs  = (float*)(ws + 163840);
  int*   topi   = (int*)  (ws + 164096);
  float* wts    = (float*)(ws + 164352);
  int*   flags  = (int*)  (ws + 164608);
  float* dpart  = (float*)(ws + 164864);           // 8*32*3 floats
  // big regions (byte offsets)
  unsigned short* hid_bf = (unsigned short*)(ws + 262144);                           // 8.39MB
  unsigned short* Wt     = (unsigned short*)(ws + 262144 + 8388608);                 // 67.1MB: W1t -> W2t -> q/k/vt
  unsigned short* hbuf   = (unsigned short*)(ws + 262144 + 8388608 + 67108864);      // 67.1MB: h -> ctx/att
  unsigned short* br     = (unsigned short*)(ws + 262144 + 8388608 + 134217728);     // 16.8MB
  unsigned short* wqkvo  = (unsigned short*)(ws + 262144 + 8388608 + 134217728 + 16777216); // 8.4MB
  unsigned short* qb  = Wt;                     // element offsets (ushort)
  unsigned short* kbf = Wt + 8388608;
  unsigned short* vt  = Wt + 16777216;
  unsigned short* ctx = hbuf;
  unsigned short* att = hbuf + 8388608;
  unsigned short* wqt = wqkvo;
  unsigned short* wkt = wqkvo + 1048576;
  unsigned short* wvt = wqkvo + 2097152;
  unsigned short* wot = wqkvo + 3145728;

  // 1. router path
  pool_part_k<<<dim3(Bn, 4), 256, 0, stream>>>(hidden, ppart);
  pool_final_k<<<dim3(32), 256, 0, stream>>>(ppart, pooled);
  router_k<<<1, 64, 0, stream>>>(pooled, router_w, router_b, probs, topi, wts, flags, out + OUT_COMBINED);

  // 2. bf16 conversions / transposes
  cvt_k<<<4096, 256, 0, stream>>>(hidden, hid_bf);
  transpose_k<<<dim3(128, 32, Tn), 256, 0, stream>>>(W1, Wt, Hn, FFn, (long)Hn * FFn, (long)FFn * Hn, flags);
  transpose_k<<<dim3(32, 32, 1), 256, 0, stream>>>(Wq, wqt, Hn, Hn, 0, 0, nullptr);
  transpose_k<<<dim3(32, 32, 1), 256, 0, stream>>>(Wk, wkt, Hn, Hn, 0, 0, nullptr);
  transpose_k<<<dim3(32, 32, 1), 256, 0, stream>>>(Wv, wvt, Hn, Hn, 0, 0, nullptr);
  transpose_k<<<dim3(32, 32, 1), 256, 0, stream>>>(Wo, wot, Hn, Hn, 0, 0, nullptr);

  // 3. FFN1 (gelu) : per pair z: A=hid_bf[b], Bt=W1t[t], C=h[z]
  gemm_k<1, 0><<<dim3(FFn / 128, Sn / 128, 16), 256, 0, stream>>>(
      hid_bf, Wt, b1, hbuf, FFn, Hn, topi, 2,
      (long)Sn * Hn, 0L, (long)FFn * Hn, FFn, (long)Sn * FFn);

  // 4. W2 transpose reuses Wt region (W1t dead)
  transpose_k<<<dim3(32, 128, Tn), 256, 0, stream>>>(W2, Wt, FFn, Hn, (long)FFn * Hn, (long)Hn * FFn, flags);

  // 5. FFN2 : A=h[z], Bt=W2t[t], C=br[z]
  gemm_k<0, 0><<<dim3(Hn / 128, Sn / 128, 16), 256, 0, stream>>>(
      hbuf, Wt, b2, br, Hn, FFn, topi, 2,
      0L, (long)Sn * FFn, (long)Hn * FFn, Hn, (long)Sn * Hn);

  // 6. diversity from branch_out
  div_part_k<<<dim3(32, Bn), 256, 0, stream>>>(br, dpart);
  div_final_k<<<1, 64, 0, stream>>>(dpart, out + OUT_COMBINED + 1);

  // 7. QKV projections (v transposed for flash)
  gemm_k<0, 0><<<dim3(Hn / 128, (Bn * Ln) / 128, 1), 256, 0, stream>>>(
      br, wqt, bq, qb, Hn, Hn, nullptr, 0, 0L, 0L, 0L, 0, 0L);
  gemm_k<0, 0><<<dim3(Hn / 128, (Bn * Ln) / 128, 1), 256, 0, stream>>>(
      br, wkt, bk, kbf, Hn, Hn, nullptr, 0, 0L, 0L, 0L, 0, 0L);
  gemm_k<0, 1><<<dim3(Hn / 128, (Bn * Ln) / 128, 1), 256, 0, stream>>>(
      br, wvt, bv, vt, Hn, Hn, nullptr, 0, 0L, 0L, 0L, 0, 0L);

  // 8. flash attention
  flash_k<<<dim3(Ln / 64, NHn, Bn), 256, 0, stream>>>(qb, kbf, vt, ctx);

  // 9. output projection
  gemm_k<0, 0><<<dim3(Hn / 128, (Bn * Ln) / 128, 1), 256, 0, stream>>>(
      ctx, wot, bo, att, Hn, Hn, nullptr, 0, 0L, 0L, 0L, 0, 0L);

  // 10. weighted combine -> f32 output
  combine_k<<<2048, 256, 0, stream>>>(att, wts, out);
}

// Round 2
// 558.817 us; speedup vs baseline: 1.1226x; 1.1226x over previous
//
#include <hip/hip_runtime.h>
#include <hip/hip_bf16.h>
#include <math.h>

typedef float f32x4 __attribute__((ext_vector_type(4)));
typedef short s16x8 __attribute__((ext_vector_type(8)));
typedef short s16x4 __attribute__((ext_vector_type(4)));
typedef unsigned int u32;

#define DEVI __device__ __forceinline__

// ---- sizes ----
#define Bn   8
#define Sn   512
#define Hn   1024
#define Tn   8
#define Kn   2
#define FFn  4096
#define NHn  8
#define HDn  128
#define Ln   1024            // K*S
#define OUT_COMBINED 4194304 // B*S*H

DEVI unsigned short f2bf(float x) {
  __hip_bfloat16 h = __float2bfloat16(x);
  union { __hip_bfloat16 h; unsigned short u; } cv; cv.h = h; return cv.u;
}
DEVI float bf2f(unsigned short u) {
  union { u32 i; float f; } cv; cv.i = ((u32)u) << 16; return cv.f;
}

typedef __attribute__((address_space(3))) u32 lds_u32;
typedef __attribute__((address_space(1))) u32 glb_u32;
DEVI void gload16(const void* g, void* l) {
  __builtin_amdgcn_global_load_lds((const glb_u32*)g, (lds_u32*)l, 16, 0, 0);
}

// ---------------- pool (mean over S) ----------------
__global__ __launch_bounds__(256) void pool_part_k(const float* __restrict__ hid, float* __restrict__ part)
{
  const int b = blockIdx.x, scn = blockIdx.y;
  const int hh = threadIdx.x * 4;
  float4 acc = make_float4(0.f, 0.f, 0.f, 0.f);
  const float* base = hid + ((long)b * Sn + (long)scn * 128) * Hn + hh;
  for (int s = 0; s < 128; ++s) {
    float4 v = *(const float4*)(base + (long)s * Hn);
    acc.x += v.x; acc.y += v.y; acc.z += v.z; acc.w += v.w;
  }
  *(float4*)(part + ((long)(scn * Bn + b)) * Hn + hh) = acc;
}

__global__ __launch_bounds__(256) void pool_final_k(const float* __restrict__ part, float* __restrict__ pooled)
{
  const int i = blockIdx.x * 256 + threadIdx.x;
  float s = 0.f;
  for (int sc = 0; sc < 4; ++sc) s += part[sc * (Bn * Hn) + i];
  pooled[i] = s * (1.f / (float)Sn);
}

// ---------------- router + entropy ----------------
__global__ __launch_bounds__(64) void router_k(
    const float* __restrict__ pooled, const float* __restrict__ rw, const float* __restrict__ rb,
    float* __restrict__ probs, int* __restrict__ topi, float* __restrict__ wts,
    int* __restrict__ flags, float* __restrict__ entropy_out)
{
  __shared__ float lg[64];
  __shared__ int sfl[8];
  __shared__ float sent[8];
  const int tid = threadIdx.x;
  const int b = tid >> 3, t = tid & 7;
  if (tid < 8) sfl[tid] = 0;
  float acc = rb[t];
  const float* pb = pooled + b * Hn;
  for (int i = 0; i < Hn; ++i) acc += pb[i] * rw[i * Tn + t];
  lg[tid] = acc;
  __syncthreads();
  if (t == 0) {
    float p[8];
    float mx = lg[b * 8];
    for (int i = 1; i < 8; ++i) mx = fmaxf(mx, lg[b * 8 + i]);
    float ssum = 0.f;
    for (int i = 0; i < 8; ++i) { p[i] = expf(lg[b * 8 + i] - mx); ssum += p[i]; }
    float ent = 0.f;
    for (int i = 0; i < 8; ++i) { p[i] /= ssum; ent -= p[i] * logf(p[i] + 1e-8f); probs[b * 8 + i] = p[i]; }
    sent[b] = ent;
    int i1 = 0;
    for (int i = 1; i < 8; ++i) if (p[i] > p[i1]) i1 = i;   // strict > : lowest index on ties (lax.top_k)
    int i2 = (i1 == 0) ? 1 : 0;
    for (int i = 0; i < 8; ++i) if (i != i1 && p[i] > p[i2]) i2 = i;
    // weights = softmax over the two top PROBS (reference applies softmax to top_p)
    float w0 = 1.f / (1.f + expf(p[i2] - p[i1]));
    float w1 = 1.f / (1.f + expf(p[i1] - p[i2]));
    topi[b * 2] = i1; topi[b * 2 + 1] = i2;
    wts[b * 2] = w0; wts[b * 2 + 1] = w1;
    atomicOr(&sfl[i1], 1); atomicOr(&sfl[i2], 1);
  }
  __syncthreads();
  if (tid < 8) flags[tid] = sfl[tid];
  if (tid == 0) {
    float e = 0.f;
    for (int i = 0; i < 8; ++i) e += sent[i];
    entropy_out[0] = e * (1.f / (float)Bn);
  }
}

// ---------------- f32 -> bf16 convert ----------------
__global__ __launch_bounds__(256) void cvt_k(const float* __restrict__ in, unsigned short* __restrict__ out)
{
  const long i = ((long)blockIdx.x * 256 + threadIdx.x) * 4;
  float4 v = *(const float4*)(in + i);
  s16x4 o;
  o[0] = (short)f2bf(v.x); o[1] = (short)f2bf(v.y); o[2] = (short)f2bf(v.z); o[3] = (short)f2bf(v.w);
  *(s16x4*)(out + i) = o;
}

// ---------------- bias concat for fused QKV ----------------
__global__ __launch_bounds__(256) void bias3_k(const float* __restrict__ bq, const float* __restrict__ bk,
                                               const float* __restrict__ bv, float* __restrict__ o)
{
  const int i = blockIdx.x * 256 + threadIdx.x;   // 0..1023
  o[i] = bq[i]; o[i + 1024] = bk[i]; o[i + 2048] = bv[i];
}

// ---------------- transpose+convert: in f32 [Kd][N] -> out bf16 [N][Kd], 64x64 tiles ----------------
__global__ __launch_bounds__(256) void transpose_k(const float* __restrict__ Win, unsigned short* __restrict__ Wout,
                                                   int Kd, int N, long sIn, long sOut, const int* __restrict__ flags)
{
  const int t = blockIdx.z;
  if (flags && flags[t] == 0) return;   // uniform per block
  __shared__ float tile[64][65];
  const float* in = Win + (long)t * sIn;
  unsigned short* out = Wout + (long)t * sOut;
  const int kb = blockIdx.y * 64, nb = blockIdx.x * 64;
  const int tx = threadIdx.x & 15, ty = threadIdx.x >> 4;
  #pragma unroll
  for (int i = 0; i < 4; ++i) {
    const int r = ty + i * 16;
    float4 v = *(const float4*)(in + (long)(kb + r) * N + nb + tx * 4);
    tile[r][tx * 4 + 0] = v.x; tile[r][tx * 4 + 1] = v.y;
    tile[r][tx * 4 + 2] = v.z; tile[r][tx * 4 + 3] = v.w;
  }
  __syncthreads();
  #pragma unroll
  for (int i = 0; i < 4; ++i) {
    const int n = ty + i * 16;
    s16x4 o;
    #pragma unroll
    for (int j = 0; j < 4; ++j) o[j] = (short)f2bf(tile[tx * 4 + j][n]);
    *(s16x4*)(out + (long)(nb + n) * Kd + kb + tx * 4) = o;
  }
}

// ---------------- GEMM: C[M,N](bf16) = A[M,Kd](bf16) @ Bt[N,Kd]^T (bf16) + bias ----------------
// 128x128 tile, BK=32, 2-phase double-buffered global_load_lds staging, LDS epilogue.
// EPI: 0 none, 1 exact gelu.
// OUTMODE: 0 normal [M][N]; 1 fused-QKV: n<2048 -> q/k [M][1024], n>=2048 -> vt[(b*1024+n')][ltok]
template<int EPI, int OUTMODE>
__global__ __launch_bounds__(256) void gemm_k(
    const unsigned short* __restrict__ A0, const unsigned short* __restrict__ Bt0,
    const float* __restrict__ bias0, unsigned short* __restrict__ C0,
    int N, int Kd,
    const int* __restrict__ topi, int kTop,
    long sA_b, long sA_p, long sBt_t, int sBias_t, long sC_p)
{
  // LDS: A dbuf [2][128][32] @0/8192 ; B dbuf @16384/24576 ; epilogue tiles (4 waves x 64x72 shorts)
  __shared__ __align__(16) char smem[36864];
  const int z = blockIdx.z;
  const int bidx = kTop ? (z / kTop) : 0;
  const int t = topi ? topi[z] : 0;
  const unsigned short* A = A0 + (long)bidx * sA_b + (long)z * sA_p;
  const unsigned short* Bt = Bt0 + (long)t * sBt_t;
  const float* bias = bias0 + (long)t * sBias_t;
  unsigned short* C = C0 + (long)z * sC_p;

  const int m0 = blockIdx.y * 128;
  const int n0 = blockIdx.x * 128;
  const int tid = threadIdx.x;
  const int lane = tid & 63, w = tid >> 6;
  const int wm = w >> 1, wn = w & 1;

  // staging: wave w owns rows [w*32, w*32+32); 2 x 16B/lane per matrix per iter.
  // LDS linear [row][32 bf16]; XOR swizzle chunk ^= (row^(row>>2))&3 applied on the GLOBAL source.
  const int srow = w * 32 + (lane >> 2);
  const int csw = ((lane & 3) ^ ((srow ^ (srow >> 2)) & 3)) << 4;

  const char* gA0 = (const char*)(A + (long)(m0 + srow) * Kd) + csw;
  const char* gA1 = (const char*)(A + (long)(m0 + srow + 16) * Kd) + csw;
  const char* gB0 = (const char*)(Bt + (long)(n0 + srow) * Kd) + csw;
  const char* gB1 = (const char*)(Bt + (long)(n0 + srow + 16) * Kd) + csw;

  char* ldsAw = smem + w * 2048;           // within A buf0
  char* ldsBw = smem + 16384 + w * 2048;   // within B buf0

  f32x4 acc[4][4];
  const f32x4 zero = {0.f, 0.f, 0.f, 0.f};
  #pragma unroll
  for (int i = 0; i < 4; ++i)
    #pragma unroll
    for (int j = 0; j < 4; ++j) acc[i][j] = zero;

  const int rA = lane & 15;
  const int cb = (lane >> 4) << 4;
  int aoff[4], boff[4];
  #pragma unroll
  for (int mi = 0; mi < 4; ++mi) {
    int row = wm * 64 + mi * 16 + rA;
    aoff[mi] = row * 64 + (cb ^ (((row ^ (row >> 2)) & 3) << 4));
    int rowb = wn * 64 + mi * 16 + rA;
    boff[mi] = rowb * 64 + (cb ^ (((rowb ^ (rowb >> 2)) & 3) << 4));
  }

  const int nIter = Kd >> 5;
  // prologue: stage iter 0 into buf 0
  gload16(gA0, ldsAw);
  gload16(gA1, ldsAw + 1024);
  gload16(gB0, ldsBw);
  gload16(gB1, ldsBw + 1024);
  __syncthreads();                 // compiler emits vmcnt(0) drain before s_barrier

  int cur = 0;
  for (int it = 0; it < nIter; ++it) {
    if (it + 1 < nIter) {          // issue next tile BEFORE compute -> overlaps MFMA
      const long kb2 = (long)(it + 1) * 64;
      const int nb = cur ^ 1;
      gload16(gA0 + kb2, ldsAw + nb * 8192);
      gload16(gA1 + kb2, ldsAw + nb * 8192 + 1024);
      gload16(gB0 + kb2, ldsBw + nb * 8192);
      gload16(gB1 + kb2, ldsBw + nb * 8192 + 1024);
    }
    const char* pa = smem + cur * 8192;
    const char* pb = smem + 16384 + cur * 8192;
    s16x8 af[4], bfr[4];
    #pragma unroll
    for (int mi = 0; mi < 4; ++mi) af[mi] = *(const s16x8*)(pa + aoff[mi]);
    #pragma unroll
    for (int nj = 0; nj < 4; ++nj) bfr[nj] = *(const s16x8*)(pb + boff[nj]);
    __builtin_amdgcn_s_setprio(1);
    #pragma unroll
    for (int mi = 0; mi < 4; ++mi)
      #pragma unroll
      for (int nj = 0; nj < 4; ++nj)
        acc[mi][nj] = __builtin_amdgcn_mfma_f32_16x16x32_bf16(af[mi], bfr[nj], acc[mi][nj], 0, 0, 0);
    __builtin_amdgcn_s_setprio(0);
    __syncthreads();               // drains next-buf loads + releases cur buf for overwrite
    cur ^= 1;
  }

  // ---- epilogue via per-wave LDS tile (64x64, pitch 72 shorts = 144B, b128-aligned) ----
  unsigned short* et = (unsigned short*)(smem + w * 9216);
  const int r4 = (lane >> 4) << 2;
  const int nbase = n0 + wn * 64;
  const int seg = nbase >> 10;            // OUTMODE 1 only
  #pragma unroll
  for (int nj = 0; nj < 4; ++nj) {
    const int n = nbase + nj * 16 + rA;
    const float bv = bias[n];
    #pragma unroll
    for (int mi = 0; mi < 4; ++mi) {
      #pragma unroll
      for (int j = 0; j < 4; ++j) {
        float x = acc[mi][nj][j] + bv;
        if (EPI == 1) x = 0.5f * x * (1.0f + erff(x * 0.70710678118654752f));
        const int mrl = mi * 16 + r4 + j;       // 0..63 within wave tile (m)
        const int ncl = nj * 16 + rA;           // 0..63 within wave tile (n)
        if (OUTMODE == 0 || seg < 2) et[mrl * 72 + ncl] = f2bf(x);
        else                         et[ncl * 72 + mrl] = f2bf(x);   // transposed for V
      }
    }
  }
  // per-wave tile: no cross-wave barrier needed (compiler orders ds_write->ds_read)
  const int erow = lane >> 3, echunk = lane & 7;
  if (OUTMODE == 0) {
    const long r0 = m0 + wm * 64;
    #pragma unroll
    for (int rr = 0; rr < 8; ++rr) {
      const int row = rr * 8 + erow;
      s16x8 v = *(const s16x8*)(et + row * 72 + echunk * 8);
      *(s16x8*)(C + (r0 + row) * N + nbase + echunk * 8) = v;
    }
  } else {
    const int nseg = nbase & 1023;
    if (seg < 2) {
      unsigned short* dst = C + (long)seg * 8388608;
      const long r0 = m0 + wm * 64;
      #pragma unroll
      for (int rr = 0; rr < 8; ++rr) {
        const int row = rr * 8 + erow;
        s16x8 v = *(const s16x8*)(et + row * 72 + echunk * 8);
        *(s16x8*)(dst + (r0 + row) * 1024 + nseg + echunk * 8) = v;
      }
    } else {
      unsigned short* vtp = C + 16777216;
      const int bb = m0 >> 10;
      const int ltok0 = (m0 & 1023) + wm * 64;
      #pragma unroll
      for (int rr = 0; rr < 8; ++rr) {
        const int nrow = rr * 8 + erow;
        s16x8 v = *(const s16x8*)(et + nrow * 72 + echunk * 8);
        *(s16x8*)(vtp + ((long)(bb * 1024 + nseg + nrow)) * 1024 + ltok0 + echunk * 8) = v;
      }
    }
  }
}

// ---------------- flash attention ----------------
// q,k: [B*L][H] bf16 ; vt: [B*NH*HD][L] bf16 ; ctx: [B*L][H] bf16
__global__ __launch_bounds__(256) void flash_k(
    const unsigned short* __restrict__ q, const unsigned short* __restrict__ k,
    const unsigned short* __restrict__ vt, unsigned short* __restrict__ ctx)
{
  __shared__ unsigned short Ks[64 * 128];   // [kv][hd], rows 256B, chunk^=(row&7)
  __shared__ unsigned short Vs[128 * 64];   // [hd][kv], rows 128B, chunk^=(row&7)
  __shared__ unsigned short Ps[4][16 * 72]; // per-wave P, pitch 72 bf16 (144B)
  const int qt = blockIdx.x, h = blockIdx.y, b = blockIdx.z;
  const int tid = threadIdx.x, lane = tid & 63, w = tid >> 6;
  const int q0 = qt * 64;
  const int rA = lane & 15;

  const int qrow = q0 + w * 16 + rA;
  const unsigned short* qp = q + ((long)(b * Ln + qrow)) * Hn + h * HDn + ((lane >> 4) * 8);
  s16x8 qf[4];
  #pragma unroll
  for (int kk = 0; kk < 4; ++kk) qf[kk] = *(const s16x8*)(qp + kk * 32);

  f32x4 o[8];
  const f32x4 zero = {0.f, 0.f, 0.f, 0.f};
  #pragma unroll
  for (int i = 0; i < 8; ++i) o[i] = zero;
  float mrun[4], lrun[4];
  #pragma unroll
  for (int j = 0; j < 4; ++j) { mrun[j] = -1e30f; lrun[j] = 0.f; }

  const float sc = 0.08838834764831845f * 1.4426950408889634f;  // 1/sqrt(128) * log2(e)

  const int krow0 = w * 16 + (lane >> 4);
  const int kc = lane & 15;
  const int vrow0 = w * 32 + (lane >> 3);
  const int vc = lane & 7;

  for (int kvt = 0; kvt < 16; ++kvt) {
    const int kv0 = kvt * 64;
    __syncthreads();
    #pragma unroll
    for (int qq = 0; qq < 4; ++qq) {
      const int rk = krow0 + qq * 4;
      gload16(k + ((long)(b * Ln + kv0 + rk)) * Hn + h * HDn + ((kc ^ (rk & 7)) * 8),
              (char*)Ks + w * 4096 + qq * 1024);
      const int rv = vrow0 + qq * 8;
      gload16(vt + ((long)(b * 1024 + h * HDn + rv)) * Ln + kv0 + ((vc ^ (rv & 7)) * 8),
              (char*)Vs + w * 4096 + qq * 1024);
    }
    __syncthreads();

    f32x4 sacc[4];
    #pragma unroll
    for (int nj = 0; nj < 4; ++nj) sacc[nj] = zero;
    #pragma unroll
    for (int kk = 0; kk < 4; ++kk) {
      #pragma unroll
      for (int nj = 0; nj < 4; ++nj) {
        const int row = nj * 16 + rA;
        const int byt = row * 256 + (((kk * 4 + (lane >> 4)) ^ (row & 7)) << 4);
        s16x8 kf = *(const s16x8*)((const char*)Ks + byt);
        sacc[nj] = __builtin_amdgcn_mfma_f32_16x16x32_bf16(qf[kk], kf, sacc[nj], 0, 0, 0);
      }
    }

    #pragma unroll
    for (int j = 0; j < 4; ++j) {
      float s0 = sacc[0][j] * sc, s1 = sacc[1][j] * sc, s2 = sacc[2][j] * sc, s3 = sacc[3][j] * sc;
      float tmax = fmaxf(fmaxf(s0, s1), fmaxf(s2, s3));
      #pragma unroll
      for (int mm = 1; mm < 16; mm <<= 1) tmax = fmaxf(tmax, __shfl_xor(tmax, mm, 64));
      const float mn = fmaxf(mrun[j], tmax);
      const float al = exp2f(mrun[j] - mn);
      mrun[j] = mn;
      float p0 = exp2f(s0 - mn), p1 = exp2f(s1 - mn), p2 = exp2f(s2 - mn), p3 = exp2f(s3 - mn);
      float ts = p0 + p1 + p2 + p3;
      #pragma unroll
      for (int mm = 1; mm < 16; mm <<= 1) ts += __shfl_xor(ts, mm, 64);
      lrun[j] = lrun[j] * al + ts;
      #pragma unroll
      for (int nn = 0; nn < 8; ++nn) o[nn][j] *= al;
      const int prow = ((lane >> 4) * 4 + j) * 72;
      Ps[w][prow + 0 * 16 + rA] = f2bf(p0);
      Ps[w][prow + 1 * 16 + rA] = f2bf(p1);
      Ps[w][prow + 2 * 16 + rA] = f2bf(p2);
      Ps[w][prow + 3 * 16 + rA] = f2bf(p3);
    }

    s16x8 pf[2];
    #pragma unroll
    for (int kk2 = 0; kk2 < 2; ++kk2)
      pf[kk2] = *(const s16x8*)((const char*)&Ps[w][0] + rA * 144 + kk2 * 64 + ((lane >> 4) << 4));
    #pragma unroll
    for (int kk2 = 0; kk2 < 2; ++kk2) {
      #pragma unroll
      for (int nn = 0; nn < 8; ++nn) {
        const int row = nn * 16 + rA;
        const int byt = row * 128 + (((kk2 * 4 + (lane >> 4)) ^ (row & 7)) << 4);
        s16x8 vf = *(const s16x8*)((const char*)Vs + byt);
        o[nn] = __builtin_amdgcn_mfma_f32_16x16x32_bf16(pf[kk2], vf, o[nn], 0, 0, 0);
      }
    }
  }

  #pragma unroll
  for (int nn = 0; nn < 8; ++nn) {
    #pragma unroll
    for (int j = 0; j < 4; ++j) {
      const int row = q0 + w * 16 + ((lane >> 4) << 2) + j;
      ctx[((long)(b * Ln + row)) * Hn + h * HDn + nn * 16 + rA] = f2bf(o[nn][j] / lrun[j]);
    }
  }
}

// ---------------- diversity ----------------
__global__ __launch_bounds__(256) void div_part_k(const unsigned short* __restrict__ br, float* __restrict__ part)
{
  const int b = blockIdx.y, ch = blockIdx.x;
  const unsigned short* a = br + (long)b * (2L * Sn * Hn);
  const unsigned short* c = a + (long)Sn * Hn;
  const int base = ch * 16384 + threadIdx.x * 8;
  float dot = 0.f, na = 0.f, nb = 0.f;
  #pragma unroll
  for (int i = 0; i < 8; ++i) {
    const int idx = base + i * 2048;
    s16x8 av = *(const s16x8*)(a + idx);
    s16x8 cv = *(const s16x8*)(c + idx);
    #pragma unroll
    for (int e = 0; e < 8; ++e) {
      float fa = bf2f((unsigned short)av[e]);
      float fc = bf2f((unsigned short)cv[e]);
      dot += fa * fc; na += fa * fa; nb += fc * fc;
    }
  }
  #pragma unroll
  for (int mm = 1; mm < 64; mm <<= 1) {
    dot += __shfl_xor(dot, mm, 64);
    na  += __shfl_xor(na, mm, 64);
    nb  += __shfl_xor(nb, mm, 64);
  }
  __shared__ float red[12];
  const int lane = threadIdx.x & 63, w = threadIdx.x >> 6;
  if (lane == 0) { red[w * 3] = dot; red[w * 3 + 1] = na; red[w * 3 + 2] = nb; }
  __syncthreads();
  if (threadIdx.x == 0) {
    float d = 0, x = 0, y = 0;
    for (int i = 0; i < 4; ++i) { d += red[i * 3]; x += red[i * 3 + 1]; y += red[i * 3 + 2]; }
    float* op = part + ((long)(b * 32 + ch)) * 3;
    op[0] = d; op[1] = x; op[2] = y;
  }
}

__global__ __launch_bounds__(64) void div_final_k(const float* __restrict__ part, float* __restrict__ outp)
{
  __shared__ float cosr[8];
  const int tid = threadIdx.x;
  if (tid < 8) {
    float d = 0, x = 0, y = 0;
    for (int i = 0; i < 32; ++i) {
      const float* p = part + ((long)(tid * 32 + i)) * 3;
      d += p[0]; x += p[1]; y += p[2];
    }
    cosr[tid] = d / fmaxf(sqrtf(x) * sqrtf(y), 1e-8f);
  }
  __syncthreads();
  if (tid == 0) {
    float s = 0.f;
    for (int i = 0; i < 8; ++i) s += 1.f - cosr[i];
    outp[0] = s * (1.f / 8.f);
  }
}

// ---------------- weighted combine ----------------
__global__ __launch_bounds__(256) void combine_k(const unsigned short* __restrict__ att,
                                                 const float* __restrict__ wts, float* __restrict__ out)
{
  const long i = ((long)blockIdx.x * 256 + threadIdx.x) * 8;
  const int b = (int)(i >> 19);           // S*H = 524288
  const long rem = i & 524287;
  const unsigned short* a0 = att + (long)b * (2L * Sn * Hn) + rem;
  const unsigned short* a1 = a0 + (long)Sn * Hn;
  const float w0 = wts[b * 2], w1 = wts[b * 2 + 1];
  s16x8 v0 = *(const s16x8*)a0;
  s16x8 v1 = *(const s16x8*)a1;
  float r[8];
  #pragma unroll
  for (int e = 0; e < 8; ++e) r[e] = w0 * bf2f((unsigned short)v0[e]) + w1 * bf2f((unsigned short)v1[e]);
  *(float4*)(out + i)     = make_float4(r[0], r[1], r[2], r[3]);
  *(float4*)(out + i + 4) = make_float4(r[4], r[5], r[6], r[7]);
}

// ---------------- launch ----------------
extern "C" void kernel_launch(void* const* d_in, const int* in_sizes, int n_in,
                              void* d_out, int out_size, void* d_ws, size_t ws_size,
                              hipStream_t stream)
{
  (void)in_sizes; (void)n_in; (void)out_size; (void)ws_size;
  const float* hidden   = (const float*)d_in[0];
  const float* router_w = (const float*)d_in[1];
  const float* router_b = (const float*)d_in[2];
  const float* W1 = (const float*)d_in[3];
  const float* b1 = (const float*)d_in[4];
  const float* W2 = (const float*)d_in[5];
  const float* b2 = (const float*)d_in[6];
  const float* Wq = (const float*)d_in[7];
  const float* bq = (const float*)d_in[8];
  const float* Wk = (const float*)d_in[9];
  const float* bk = (const float*)d_in[10];
  const float* Wv = (const float*)d_in[11];
  const float* bv = (const float*)d_in[12];
  const float* Wo = (const float*)d_in[13];
  const float* bo = (const float*)d_in[14];
  float* out = (float*)d_out;

  char* ws = (char*)d_ws;
  // small region (<256KB)
  float* pooled  = (float*)(ws);                    // 32KB
  float* ppart   = (float*)(ws + 32768);            // 128KB
  float* probs   = (float*)(ws + 163840);
  int*   topi    = (int*)  (ws + 164096);
  float* wts     = (float*)(ws + 164352);
  int*   flags   = (int*)  (ws + 164608);
  float* dpart   = (float*)(ws + 164864);           // 3KB
  float* qkvbias = (float*)(ws + 167936);           // 12KB
  // big regions (byte offsets)
  unsigned short* hid_bf = (unsigned short*)(ws + 262144);                           // 8.39MB
  unsigned short* Wt     = (unsigned short*)(ws + 262144 + 8388608);                 // 67.1MB: W1t -> W2t -> q/k/vt
  unsigned short* hbuf   = (unsigned short*)(ws + 262144 + 8388608 + 67108864);      // 67.1MB: h -> ctx/att
  unsigned short* br     = (unsigned short*)(ws + 262144 + 8388608 + 134217728);     // 16.8MB
  unsigned short* wqkvo  = (unsigned short*)(ws + 262144 + 8388608 + 134217728 + 16777216); // 8.4MB
  unsigned short* qb  = Wt;                     // q/k/vt contiguous (fused epilogue relies on this)
  unsigned short* kbf = Wt + 8388608;
  unsigned short* vt  = Wt + 16777216;
  unsigned short* ctx = hbuf;
  unsigned short* att = hbuf + 8388608;
  unsigned short* wqt = wqkvo;                  // rows 0-1023 of fused [3072][1024]
  unsigned short* wkt = wqkvo + 1048576;        // rows 1024-2047
  unsigned short* wvt = wqkvo + 2097152;        // rows 2048-3071
  unsigned short* wot = wqkvo + 3145728;

  // 1. router path
  pool_part_k<<<dim3(Bn, 4), 256, 0, stream>>>(hidden, ppart);
  pool_final_k<<<dim3(32), 256, 0, stream>>>(ppart, pooled);
  router_k<<<1, 64, 0, stream>>>(pooled, router_w, router_b, probs, topi, wts, flags, out + OUT_COMBINED);

  // 2. bf16 conversions / transposes
  cvt_k<<<4096, 256, 0, stream>>>(hidden, hid_bf);
  bias3_k<<<4, 256, 0, stream>>>(bq, bk, bv, qkvbias);
  transpose_k<<<dim3(64, 16, Tn), 256, 0, stream>>>(W1, Wt, Hn, FFn, (long)Hn * FFn, (long)FFn * Hn, flags);
  transpose_k<<<dim3(16, 16, 1), 256, 0, stream>>>(Wq, wqt, Hn, Hn, 0, 0, nullptr);
  transpose_k<<<dim3(16, 16, 1), 256, 0, stream>>>(Wk, wkt, Hn, Hn, 0, 0, nullptr);
  transpose_k<<<dim3(16, 16, 1), 256, 0, stream>>>(Wv, wvt, Hn, Hn, 0, 0, nullptr);
  transpose_k<<<dim3(16, 16, 1), 256, 0, stream>>>(Wo, wot, Hn, Hn, 0, 0, nullptr);

  // 3. FFN1 (gelu) : per pair z: A=hid_bf[b], Bt=W1t[t], C=h[z]
  gemm_k<1, 0><<<dim3(FFn / 128, Sn / 128, 16), 256, 0, stream>>>(
      hid_bf, Wt, b1, hbuf, FFn, Hn, topi, 2,
      (long)Sn * Hn, 0L, (long)FFn * Hn, FFn, (long)Sn * FFn);

  // 4. W2 transpose reuses Wt region (W1t dead)
  transpose_k<<<dim3(16, 64, Tn), 256, 0, stream>>>(W2, Wt, FFn, Hn, (long)FFn * Hn, (long)Hn * FFn, flags);

  // 5. FFN2 : A=h[z], Bt=W2t[t], C=br[z]
  gemm_k<0, 0><<<dim3(Hn / 128, Sn / 128, 16), 256, 0, stream>>>(
      hbuf, Wt, b2, br, Hn, FFn, topi, 2,
      0L, (long)Sn * FFn, (long)Hn * FFn, Hn, (long)Sn * Hn);

  // 6. diversity from branch_out
  div_part_k<<<dim3(32, Bn), 256, 0, stream>>>(br, dpart);
  div_final_k<<<1, 64, 0, stream>>>(dpart, out + OUT_COMBINED + 1);

  // 7. fused QKV projection (N=3072; q/k normal, v transposed for flash)
  gemm_k<0, 1><<<dim3(3072 / 128, (Bn * Ln) / 128, 1), 256, 0, stream>>>(
      br, wqkvo, qkvbias, qb, 3072, Hn, nullptr, 0, 0L, 0L, 0L, 0, 0L);

  // 8. flash attention
  flash_k<<<dim3(Ln / 64, NHn, Bn), 256, 0, stream>>>(qb, kbf, vt, ctx);

  // 9. output projection
  gemm_k<0, 0><<<dim3(Hn / 128, (Bn * Ln) / 128, 1), 256, 0, stream>>>(
      ctx, wot, bo, att, Hn, Hn, nullptr, 0, 0L, 0L, 0L, 0, 0L);

  // 10. weighted combine -> f32 output
  combine_k<<<2048, 256, 0, stream>>>(att, wts, out);
}

// Round 3
// 538.048 us; speedup vs baseline: 1.1659x; 1.0386x over previous
//
#include <hip/hip_runtime.h>
#include <hip/hip_bf16.h>
#include <math.h>

typedef float f32x4 __attribute__((ext_vector_type(4)));
typedef short s16x8 __attribute__((ext_vector_type(8)));
typedef short s16x4 __attribute__((ext_vector_type(4)));
typedef unsigned int u32;

#define DEVI __device__ __forceinline__

// ---- sizes ----
#define Bn   8
#define Sn   512
#define Hn   1024
#define Tn   8
#define Kn   2
#define FFn  4096
#define NHn  8
#define HDn  128
#define Ln   1024            // K*S
#define OUT_COMBINED 4194304 // B*S*H

DEVI unsigned short f2bf(float x) {
  __hip_bfloat16 h = __float2bfloat16(x);
  union { __hip_bfloat16 h; unsigned short u; } cv; cv.h = h; return cv.u;
}
DEVI float bf2f(unsigned short u) {
  union { u32 i; float f; } cv; cv.i = ((u32)u) << 16; return cv.f;
}

typedef __attribute__((address_space(3))) u32 lds_u32;
typedef __attribute__((address_space(1))) u32 glb_u32;
DEVI void gload16(const void* g, void* l) {
  __builtin_amdgcn_global_load_lds((const glb_u32*)g, (lds_u32*)l, 16, 0, 0);
}

// ---------------- pool (mean over S) ----------------
__global__ __launch_bounds__(256) void pool_part_k(const float* __restrict__ hid, float* __restrict__ part)
{
  const int b = blockIdx.x, scn = blockIdx.y;
  const int hh = threadIdx.x * 4;
  float4 acc = make_float4(0.f, 0.f, 0.f, 0.f);
  const float* base = hid + ((long)b * Sn + (long)scn * 128) * Hn + hh;
  for (int s = 0; s < 128; ++s) {
    float4 v = *(const float4*)(base + (long)s * Hn);
    acc.x += v.x; acc.y += v.y; acc.z += v.z; acc.w += v.w;
  }
  *(float4*)(part + ((long)(scn * Bn + b)) * Hn + hh) = acc;
}

__global__ __launch_bounds__(256) void pool_final_k(const float* __restrict__ part, float* __restrict__ pooled)
{
  const int i = blockIdx.x * 256 + threadIdx.x;
  float s = 0.f;
  for (int sc = 0; sc < 4; ++sc) s += part[sc * (Bn * Hn) + i];
  pooled[i] = s * (1.f / (float)Sn);
}

// ---------------- router + entropy ----------------
__global__ __launch_bounds__(64) void router_k(
    const float* __restrict__ pooled, const float* __restrict__ rw, const float* __restrict__ rb,
    float* __restrict__ probs, int* __restrict__ topi, float* __restrict__ wts,
    int* __restrict__ flags, float* __restrict__ entropy_out)
{
  __shared__ float lg[64];
  __shared__ int sfl[8];
  __shared__ float sent[8];
  const int tid = threadIdx.x;
  const int b = tid >> 3, t = tid & 7;
  if (tid < 8) sfl[tid] = 0;
  float acc = rb[t];
  const float* pb = pooled + b * Hn;
  for (int i = 0; i < Hn; ++i) acc += pb[i] * rw[i * Tn + t];
  lg[tid] = acc;
  __syncthreads();
  if (t == 0) {
    float p[8];
    float mx = lg[b * 8];
    for (int i = 1; i < 8; ++i) mx = fmaxf(mx, lg[b * 8 + i]);
    float ssum = 0.f;
    for (int i = 0; i < 8; ++i) { p[i] = expf(lg[b * 8 + i] - mx); ssum += p[i]; }
    float ent = 0.f;
    for (int i = 0; i < 8; ++i) { p[i] /= ssum; ent -= p[i] * logf(p[i] + 1e-8f); probs[b * 8 + i] = p[i]; }
    sent[b] = ent;
    int i1 = 0;
    for (int i = 1; i < 8; ++i) if (p[i] > p[i1]) i1 = i;   // strict > : lowest index on ties (lax.top_k)
    int i2 = (i1 == 0) ? 1 : 0;
    for (int i = 0; i < 8; ++i) if (i != i1 && p[i] > p[i2]) i2 = i;
    // weights = softmax over the two top PROBS (reference applies softmax to top_p)
    float w0 = 1.f / (1.f + expf(p[i2] - p[i1]));
    float w1 = 1.f / (1.f + expf(p[i1] - p[i2]));
    topi[b * 2] = i1; topi[b * 2 + 1] = i2;
    wts[b * 2] = w0; wts[b * 2 + 1] = w1;
    atomicOr(&sfl[i1], 1); atomicOr(&sfl[i2], 1);
  }
  __syncthreads();
  if (tid < 8) flags[tid] = sfl[tid];
  if (tid == 0) {
    float e = 0.f;
    for (int i = 0; i < 8; ++i) e += sent[i];
    entropy_out[0] = e * (1.f / (float)Bn);
  }
}

// ---------------- f32 -> bf16 convert ----------------
__global__ __launch_bounds__(256) void cvt_k(const float* __restrict__ in, unsigned short* __restrict__ out)
{
  const long i = ((long)blockIdx.x * 256 + threadIdx.x) * 4;
  float4 v = *(const float4*)(in + i);
  s16x4 o;
  o[0] = (short)f2bf(v.x); o[1] = (short)f2bf(v.y); o[2] = (short)f2bf(v.z); o[3] = (short)f2bf(v.w);
  *(s16x4*)(out + i) = o;
}

// ---------------- bias concat for fused QKV ----------------
__global__ __launch_bounds__(256) void bias3_k(const float* __restrict__ bq, const float* __restrict__ bk,
                                               const float* __restrict__ bv, float* __restrict__ o)
{
  const int i = blockIdx.x * 256 + threadIdx.x;   // 0..1023
  o[i] = bq[i]; o[i + 1024] = bk[i]; o[i + 2048] = bv[i];
}

// ---------------- transpose+convert: in f32 [Kd][N] -> out bf16 [N][Kd], 64x64 tiles ----------------
__global__ __launch_bounds__(256) void transpose_k(const float* __restrict__ Win, unsigned short* __restrict__ Wout,
                                                   int Kd, int N, long sIn, long sOut, const int* __restrict__ flags)
{
  const int t = blockIdx.z;
  if (flags && flags[t] == 0) return;   // uniform per block
  __shared__ float tile[64][65];
  const float* in = Win + (long)t * sIn;
  unsigned short* out = Wout + (long)t * sOut;
  const int kb = blockIdx.y * 64, nb = blockIdx.x * 64;
  const int tx = threadIdx.x & 15, ty = threadIdx.x >> 4;
  #pragma unroll
  for (int i = 0; i < 4; ++i) {
    const int r = ty + i * 16;
    float4 v = *(const float4*)(in + (long)(kb + r) * N + nb + tx * 4);
    tile[r][tx * 4 + 0] = v.x; tile[r][tx * 4 + 1] = v.y;
    tile[r][tx * 4 + 2] = v.z; tile[r][tx * 4 + 3] = v.w;
  }
  __syncthreads();
  #pragma unroll
  for (int i = 0; i < 4; ++i) {
    const int n = ty + i * 16;
    s16x4 o;
    #pragma unroll
    for (int j = 0; j < 4; ++j) o[j] = (short)f2bf(tile[tx * 4 + j][n]);
    *(s16x4*)(out + (long)(nb + n) * Kd + kb + tx * 4) = o;
  }
}

// ---------------- GEMM: C[M,N](bf16) = A[M,Kd](bf16) @ Bt[N,Kd]^T (bf16) + bias ----------------
// 128x128 tile, BK=32, 2-phase double-buffered global_load_lds staging, LDS epilogue.
// EPI: 0 none, 1 exact gelu.
// OUTMODE: 0 normal [M][N]; 1 fused-QKV: n<2048 -> q/k [M][1024], n>=2048 -> vt[(b*1024+n')][ltok]
template<int EPI, int OUTMODE>
__global__ __launch_bounds__(256) void gemm_k(
    const unsigned short* __restrict__ A0, const unsigned short* __restrict__ Bt0,
    const float* __restrict__ bias0, unsigned short* __restrict__ C0,
    int N, int Kd,
    const int* __restrict__ topi, int kTop,
    long sA_b, long sA_p, long sBt_t, int sBias_t, long sC_p)
{
  // LDS: A dbuf [2][128][32] @0/8192 ; B dbuf @16384/24576 ; epilogue tiles (4 waves x 64x72 shorts)
  __shared__ __align__(16) char smem[36864];
  const int z = blockIdx.z;
  const int bidx = kTop ? (z / kTop) : 0;
  const int t = topi ? topi[z] : 0;
  const unsigned short* A = A0 + (long)bidx * sA_b + (long)z * sA_p;
  const unsigned short* Bt = Bt0 + (long)t * sBt_t;
  const float* bias = bias0 + (long)t * sBias_t;
  unsigned short* C = C0 + (long)z * sC_p;

  const int m0 = blockIdx.y * 128;
  const int n0 = blockIdx.x * 128;
  const int tid = threadIdx.x;
  const int lane = tid & 63, w = tid >> 6;
  const int wm = w >> 1, wn = w & 1;

  // staging: wave w owns rows [w*32, w*32+32); 2 x 16B/lane per matrix per iter.
  // LDS linear [row][32 bf16]; XOR swizzle chunk ^= (row^(row>>2))&3 applied on the GLOBAL source.
  const int srow = w * 32 + (lane >> 2);
  const int csw = ((lane & 3) ^ ((srow ^ (srow >> 2)) & 3)) << 4;

  const char* gA0 = (const char*)(A + (long)(m0 + srow) * Kd) + csw;
  const char* gA1 = (const char*)(A + (long)(m0 + srow + 16) * Kd) + csw;
  const char* gB0 = (const char*)(Bt + (long)(n0 + srow) * Kd) + csw;
  const char* gB1 = (const char*)(Bt + (long)(n0 + srow + 16) * Kd) + csw;

  char* ldsAw = smem + w * 2048;           // within A buf0
  char* ldsBw = smem + 16384 + w * 2048;   // within B buf0

  f32x4 acc[4][4];
  const f32x4 zero = {0.f, 0.f, 0.f, 0.f};
  #pragma unroll
  for (int i = 0; i < 4; ++i)
    #pragma unroll
    for (int j = 0; j < 4; ++j) acc[i][j] = zero;

  const int rA = lane & 15;
  const int cb = (lane >> 4) << 4;
  int aoff[4], boff[4];
  #pragma unroll
  for (int mi = 0; mi < 4; ++mi) {
    int row = wm * 64 + mi * 16 + rA;
    aoff[mi] = row * 64 + (cb ^ (((row ^ (row >> 2)) & 3) << 4));
    int rowb = wn * 64 + mi * 16 + rA;
    boff[mi] = rowb * 64 + (cb ^ (((rowb ^ (rowb >> 2)) & 3) << 4));
  }

  const int nIter = Kd >> 5;
  // prologue: stage iter 0 into buf 0
  gload16(gA0, ldsAw);
  gload16(gA1, ldsAw + 1024);
  gload16(gB0, ldsBw);
  gload16(gB1, ldsBw + 1024);
  __syncthreads();                 // compiler emits vmcnt(0) drain before s_barrier

  int cur = 0;
  for (int it = 0; it < nIter; ++it) {
    if (it + 1 < nIter) {          // issue next tile BEFORE compute -> overlaps MFMA
      const long kb2 = (long)(it + 1) * 64;
      const int nb = cur ^ 1;
      gload16(gA0 + kb2, ldsAw + nb * 8192);
      gload16(gA1 + kb2, ldsAw + nb * 8192 + 1024);
      gload16(gB0 + kb2, ldsBw + nb * 8192);
      gload16(gB1 + kb2, ldsBw + nb * 8192 + 1024);
    }
    const char* pa = smem + cur * 8192;
    const char* pb = smem + 16384 + cur * 8192;
    s16x8 af[4], bfr[4];
    #pragma unroll
    for (int mi = 0; mi < 4; ++mi) af[mi] = *(const s16x8*)(pa + aoff[mi]);
    #pragma unroll
    for (int nj = 0; nj < 4; ++nj) bfr[nj] = *(const s16x8*)(pb + boff[nj]);
    __builtin_amdgcn_s_setprio(1);
    #pragma unroll
    for (int mi = 0; mi < 4; ++mi)
      #pragma unroll
      for (int nj = 0; nj < 4; ++nj)
        acc[mi][nj] = __builtin_amdgcn_mfma_f32_16x16x32_bf16(af[mi], bfr[nj], acc[mi][nj], 0, 0, 0);
    __builtin_amdgcn_s_setprio(0);
    __syncthreads();               // drains next-buf loads + releases cur buf for overwrite
    cur ^= 1;
  }

  // ---- epilogue via per-wave LDS tile (64x64, pitch 72 shorts = 144B, b128-aligned) ----
  unsigned short* et = (unsigned short*)(smem + w * 9216);
  const int r4 = (lane >> 4) << 2;
  const int nbase = n0 + wn * 64;
  const int seg = nbase >> 10;            // OUTMODE 1 only
  #pragma unroll
  for (int nj = 0; nj < 4; ++nj) {
    const int n = nbase + nj * 16 + rA;
    const float bv = bias[n];
    #pragma unroll
    for (int mi = 0; mi < 4; ++mi) {
      #pragma unroll
      for (int j = 0; j < 4; ++j) {
        float x = acc[mi][nj][j] + bv;
        if (EPI == 1) x = 0.5f * x * (1.0f + erff(x * 0.70710678118654752f));
        const int mrl = mi * 16 + r4 + j;       // 0..63 within wave tile (m)
        const int ncl = nj * 16 + rA;           // 0..63 within wave tile (n)
        if (OUTMODE == 0 || seg < 2) et[mrl * 72 + ncl] = f2bf(x);
        else                         et[ncl * 72 + mrl] = f2bf(x);   // transposed for V
      }
    }
  }
  // per-wave tile: no cross-wave barrier needed (compiler orders ds_write->ds_read)
  const int erow = lane >> 3, echunk = lane & 7;
  if (OUTMODE == 0) {
    const long r0 = m0 + wm * 64;
    #pragma unroll
    for (int rr = 0; rr < 8; ++rr) {
      const int row = rr * 8 + erow;
      s16x8 v = *(const s16x8*)(et + row * 72 + echunk * 8);
      *(s16x8*)(C + (r0 + row) * N + nbase + echunk * 8) = v;
    }
  } else {
    const int nseg = nbase & 1023;
    if (seg < 2) {
      unsigned short* dst = C + (long)seg * 8388608;
      const long r0 = m0 + wm * 64;
      #pragma unroll
      for (int rr = 0; rr < 8; ++rr) {
        const int row = rr * 8 + erow;
        s16x8 v = *(const s16x8*)(et + row * 72 + echunk * 8);
        *(s16x8*)(dst + (r0 + row) * 1024 + nseg + echunk * 8) = v;
      }
    } else {
      unsigned short* vtp = C + 16777216;
      const int bb = m0 >> 10;
      const int ltok0 = (m0 & 1023) + wm * 64;
      #pragma unroll
      for (int rr = 0; rr < 8; ++rr) {
        const int nrow = rr * 8 + erow;
        s16x8 v = *(const s16x8*)(et + nrow * 72 + echunk * 8);
        *(s16x8*)(vtp + ((long)(bb * 1024 + nseg + nrow)) * 1024 + ltok0 + echunk * 8) = v;
      }
    }
  }
}

// ---------------- flash attention ----------------
// 128 q rows per block (4 waves x 32), KV tile 64, defer-max (m=0) + lane-local l.
// q,k: [B*L][H] bf16 ; vt: [B*NH*HD][L] bf16 ; ctx: [B*L][H] bf16
__global__ __launch_bounds__(256) void flash_k(
    const unsigned short* __restrict__ q, const unsigned short* __restrict__ k,
    const unsigned short* __restrict__ vt, unsigned short* __restrict__ ctx)
{
  __shared__ unsigned short Ks[64 * 128];    // [kv][hd], rows 256B, chunk^=(row&7)
  __shared__ unsigned short Vs[128 * 64];    // [hd][kv], rows 128B, chunk^=(row&7)
  __shared__ unsigned short Ps[4][32 * 72];  // per-wave P [32 q][64 kv], pitch 72 (144B)
  const int qt = blockIdx.x, h = blockIdx.y, b = blockIdx.z;
  const int tid = threadIdx.x, lane = tid & 63, w = tid >> 6;
  const int rA = lane & 15, g = lane >> 4;
  const int q0w = qt * 128 + w * 32;         // wave's 32 q rows

  // Q fragments: 2 row-blocks x 4 k-chunks
  s16x8 qf[2][4];
  #pragma unroll
  for (int qi = 0; qi < 2; ++qi) {
    const unsigned short* qp = q + ((long)(b * Ln + q0w + qi * 16 + rA)) * Hn + h * HDn + g * 8;
    #pragma unroll
    for (int kk = 0; kk < 4; ++kk) qf[qi][kk] = *(const s16x8*)(qp + kk * 32);
  }

  f32x4 o[2][8];
  const f32x4 zero = {0.f, 0.f, 0.f, 0.f};
  #pragma unroll
  for (int qi = 0; qi < 2; ++qi)
    #pragma unroll
    for (int nn = 0; nn < 8; ++nn) o[qi][nn] = zero;
  float lrun[2][4];
  #pragma unroll
  for (int qi = 0; qi < 2; ++qi)
    #pragma unroll
    for (int j = 0; j < 4; ++j) lrun[qi][j] = 0.f;
  float m = 0.f;                                  // wave-uniform running max (exp2 domain)

  const float sc2 = 0.08838834764831845f * 1.4426950408889634f;  // 1/sqrt(128)*log2(e)

  const int krow0 = w * 16 + g;
  const int kc = lane & 15;
  const int vrow0 = w * 32 + (lane >> 3);
  const int vc = lane & 7;

  for (int kvt = 0; kvt < 16; ++kvt) {
    const int kv0 = kvt * 64;
    __syncthreads();
    #pragma unroll
    for (int qq = 0; qq < 4; ++qq) {
      const int rk = krow0 + qq * 4;
      gload16(k + ((long)(b * Ln + kv0 + rk)) * Hn + h * HDn + ((kc ^ (rk & 7)) * 8),
              (char*)Ks + w * 4096 + qq * 1024);
      const int rv = vrow0 + qq * 8;
      gload16(vt + ((long)(b * 1024 + h * HDn + rv)) * Ln + kv0 + ((vc ^ (rv & 7)) * 8),
              (char*)Vs + w * 4096 + qq * 1024);
    }
    __syncthreads();

    // ---- QK^T: 32 MFMA, 16 kf reads shared across both q-blocks ----
    f32x4 sacc[2][4];
    #pragma unroll
    for (int qi = 0; qi < 2; ++qi)
      #pragma unroll
      for (int nj = 0; nj < 4; ++nj) sacc[qi][nj] = zero;
    #pragma unroll
    for (int kk = 0; kk < 4; ++kk) {
      #pragma unroll
      for (int nj = 0; nj < 4; ++nj) {
        const int row = nj * 16 + rA;
        const int byt = row * 256 + (((kk * 4 + g) ^ (row & 7)) << 4);
        s16x8 kf = *(const s16x8*)((const char*)Ks + byt);
        sacc[0][nj] = __builtin_amdgcn_mfma_f32_16x16x32_bf16(qf[0][kk], kf, sacc[0][nj], 0, 0, 0);
        sacc[1][nj] = __builtin_amdgcn_mfma_f32_16x16x32_bf16(qf[1][kk], kf, sacc[1][nj], 0, 0, 0);
      }
    }

    // ---- softmax, defer-max fast path (no cross-lane ops, no rescale) ----
    float vmax = -3.0e38f;
    #pragma unroll
    for (int qi = 0; qi < 2; ++qi)
      #pragma unroll
      for (int nj = 0; nj < 4; ++nj)
        #pragma unroll
        for (int j = 0; j < 4; ++j) {
          const float s = sacc[qi][nj][j] * sc2;
          sacc[qi][nj][j] = s;
          vmax = fmaxf(vmax, s);
        }
    if (!__all(vmax <= m + 8.0f)) {
      // slow path (rare): full-wave max, rescale o and lrun
      float mn = vmax;
      #pragma unroll
      for (int mm = 1; mm < 64; mm <<= 1) mn = fmaxf(mn, __shfl_xor(mn, mm, 64));
      const float al = exp2f(m - mn);
      #pragma unroll
      for (int qi = 0; qi < 2; ++qi) {
        #pragma unroll
        for (int nn = 0; nn < 8; ++nn)
          #pragma unroll
          for (int j = 0; j < 4; ++j) o[qi][nn][j] *= al;
        #pragma unroll
        for (int j = 0; j < 4; ++j) lrun[qi][j] *= al;
      }
      m = mn;
    }
    #pragma unroll
    for (int qi = 0; qi < 2; ++qi)
      #pragma unroll
      for (int j = 0; j < 4; ++j) {
        float p0 = exp2f(sacc[qi][0][j] - m);
        float p1 = exp2f(sacc[qi][1][j] - m);
        float p2 = exp2f(sacc[qi][2][j] - m);
        float p3 = exp2f(sacc[qi][3][j] - m);
        lrun[qi][j] += (p0 + p1) + (p2 + p3);   // lane-local partial sum (own kv cols)
        const int prow = (qi * 16 + g * 4 + j) * 72;
        Ps[w][prow + 0 * 16 + rA] = f2bf(p0);
        Ps[w][prow + 1 * 16 + rA] = f2bf(p1);
        Ps[w][prow + 2 * 16 + rA] = f2bf(p2);
        Ps[w][prow + 3 * 16 + rA] = f2bf(p3);
      }

    // ---- PV: 32 MFMA, 16 vf reads shared across both q-blocks ----
    s16x8 pf[2][2];
    #pragma unroll
    for (int qi = 0; qi < 2; ++qi)
      #pragma unroll
      for (int kk2 = 0; kk2 < 2; ++kk2)
        pf[qi][kk2] = *(const s16x8*)(&Ps[w][(qi * 16 + rA) * 72 + kk2 * 32 + g * 8]);
    #pragma unroll
    for (int kk2 = 0; kk2 < 2; ++kk2) {
      #pragma unroll
      for (int nn = 0; nn < 8; ++nn) {
        const int row = nn * 16 + rA;
        const int byt = row * 128 + (((kk2 * 4 + g) ^ (row & 7)) << 4);
        s16x8 vf = *(const s16x8*)((const char*)Vs + byt);
        o[0][nn] = __builtin_amdgcn_mfma_f32_16x16x32_bf16(pf[0][kk2], vf, o[0][nn], 0, 0, 0);
        o[1][nn] = __builtin_amdgcn_mfma_f32_16x16x32_bf16(pf[1][kk2], vf, o[1][nn], 0, 0, 0);
      }
    }
  }

  // ---- final: cross-lane l reduce (once), divide, store ----
  float linv[2][4];
  #pragma unroll
  for (int qi = 0; qi < 2; ++qi)
    #pragma unroll
    for (int j = 0; j < 4; ++j) {
      float l = lrun[qi][j];
      #pragma unroll
      for (int mm = 1; mm < 16; mm <<= 1) l += __shfl_xor(l, mm, 64);
      linv[qi][j] = 1.0f / l;
    }
  #pragma unroll
  for (int qi = 0; qi < 2; ++qi)
    #pragma unroll
    for (int nn = 0; nn < 8; ++nn)
      #pragma unroll
      for (int j = 0; j < 4; ++j) {
        const int row = q0w + qi * 16 + g * 4 + j;
        ctx[((long)(b * Ln + row)) * Hn + h * HDn + nn * 16 + rA] = f2bf(o[qi][nn][j] * linv[qi][j]);
      }
}

// ---------------- diversity ----------------
__global__ __launch_bounds__(256) void div_part_k(const unsigned short* __restrict__ br, float* __restrict__ part)
{
  const int b = blockIdx.y, ch = blockIdx.x;
  const unsigned short* a = br + (long)b * (2L * Sn * Hn);
  const unsigned short* c = a + (long)Sn * Hn;
  const int base = ch * 16384 + threadIdx.x * 8;
  float dot = 0.f, na = 0.f, nb = 0.f;
  #pragma unroll
  for (int i = 0; i < 8; ++i) {
    const int idx = base + i * 2048;
    s16x8 av = *(const s16x8*)(a + idx);
    s16x8 cv = *(const s16x8*)(c + idx);
    #pragma unroll
    for (int e = 0; e < 8; ++e) {
      float fa = bf2f((unsigned short)av[e]);
      float fc = bf2f((unsigned short)cv[e]);
      dot += fa * fc; na += fa * fa; nb += fc * fc;
    }
  }
  #pragma unroll
  for (int mm = 1; mm < 64; mm <<= 1) {
    dot += __shfl_xor(dot, mm, 64);
    na  += __shfl_xor(na, mm, 64);
    nb  += __shfl_xor(nb, mm, 64);
  }
  __shared__ float red[12];
  const int lane = threadIdx.x & 63, w = threadIdx.x >> 6;
  if (lane == 0) { red[w * 3] = dot; red[w * 3 + 1] = na; red[w * 3 + 2] = nb; }
  __syncthreads();
  if (threadIdx.x == 0) {
    float d = 0, x = 0, y = 0;
    for (int i = 0; i < 4; ++i) { d += red[i * 3]; x += red[i * 3 + 1]; y += red[i * 3 + 2]; }
    float* op = part + ((long)(b * 32 + ch)) * 3;
    op[0] = d; op[1] = x; op[2] = y;
  }
}

__global__ __launch_bounds__(64) void div_final_k(const float* __restrict__ part, float* __restrict__ outp)
{
  __shared__ float cosr[8];
  const int tid = threadIdx.x;
  if (tid < 8) {
    float d = 0, x = 0, y = 0;
    for (int i = 0; i < 32; ++i) {
      const float* p = part + ((long)(tid * 32 + i)) * 3;
      d += p[0]; x += p[1]; y += p[2];
    }
    cosr[tid] = d / fmaxf(sqrtf(x) * sqrtf(y), 1e-8f);
  }
  __syncthreads();
  if (tid == 0) {
    float s = 0.f;
    for (int i = 0; i < 8; ++i) s += 1.f - cosr[i];
    outp[0] = s * (1.f / 8.f);
  }
}

// ---------------- weighted combine ----------------
__global__ __launch_bounds__(256) void combine_k(const unsigned short* __restrict__ att,
                                                 const float* __restrict__ wts, float* __restrict__ out)
{
  const long i = ((long)blockIdx.x * 256 + threadIdx.x) * 8;
  const int b = (int)(i >> 19);           // S*H = 524288
  const long rem = i & 524287;
  const unsigned short* a0 = att + (long)b * (2L * Sn * Hn) + rem;
  const unsigned short* a1 = a0 + (long)Sn * Hn;
  const float w0 = wts[b * 2], w1 = wts[b * 2 + 1];
  s16x8 v0 = *(const s16x8*)a0;
  s16x8 v1 = *(const s16x8*)a1;
  float r[8];
  #pragma unroll
  for (int e = 0; e < 8; ++e) r[e] = w0 * bf2f((unsigned short)v0[e]) + w1 * bf2f((unsigned short)v1[e]);
  *(float4*)(out + i)     = make_float4(r[0], r[1], r[2], r[3]);
  *(float4*)(out + i + 4) = make_float4(r[4], r[5], r[6], r[7]);
}

// ---------------- launch ----------------
extern "C" void kernel_launch(void* const* d_in, const int* in_sizes, int n_in,
                              void* d_out, int out_size, void* d_ws, size_t ws_size,
                              hipStream_t stream)
{
  (void)in_sizes; (void)n_in; (void)out_size; (void)ws_size;
  const float* hidden   = (const float*)d_in[0];
  const float* router_w = (const float*)d_in[1];
  const float* router_b = (const float*)d_in[2];
  const float* W1 = (const float*)d_in[3];
  const float* b1 = (const float*)d_in[4];
  const float* W2 = (const float*)d_in[5];
  const float* b2 = (const float*)d_in[6];
  const float* Wq = (const float*)d_in[7];
  const float* bq = (const float*)d_in[8];
  const float* Wk = (const float*)d_in[9];
  const float* bk = (const float*)d_in[10];
  const float* Wv = (const float*)d_in[11];
  const float* bv = (const float*)d_in[12];
  const float* Wo = (const float*)d_in[13];
  const float* bo = (const float*)d_in[14];
  float* out = (float*)d_out;

  char* ws = (char*)d_ws;
  // small region (<256KB)
  float* pooled  = (float*)(ws);                    // 32KB
  float* ppart   = (float*)(ws + 32768);            // 128KB
  float* probs   = (float*)(ws + 163840);
  int*   topi    = (int*)  (ws + 164096);
  float* wts     = (float*)(ws + 164352);
  int*   flags   = (int*)  (ws + 164608);
  float* dpart   = (float*)(ws + 164864);           // 3KB
  float* qkvbias = (float*)(ws + 167936);           // 12KB
  // big regions (byte offsets)
  unsigned short* hid_bf = (unsigned short*)(ws + 262144);                           // 8.39MB
  unsigned short* Wt     = (unsigned short*)(ws + 262144 + 8388608);                 // 67.1MB: W1t -> W2t -> q/k/vt
  unsigned short* hbuf   = (unsigned short*)(ws + 262144 + 8388608 + 67108864);      // 67.1MB: h -> ctx/att
  unsigned short* br     = (unsigned short*)(ws + 262144 + 8388608 + 134217728);     // 16.8MB
  unsigned short* wqkvo  = (unsigned short*)(ws + 262144 + 8388608 + 134217728 + 16777216); // 8.4MB
  unsigned short* qb  = Wt;                     // q/k/vt contiguous (fused epilogue relies on this)
  unsigned short* kbf = Wt + 8388608;
  unsigned short* vt  = Wt + 16777216;
  unsigned short* ctx = hbuf;
  unsigned short* att = hbuf + 8388608;
  unsigned short* wqt = wqkvo;                  // rows 0-1023 of fused [3072][1024]
  unsigned short* wkt = wqkvo + 1048576;        // rows 1024-2047
  unsigned short* wvt = wqkvo + 2097152;        // rows 2048-3071
  unsigned short* wot = wqkvo + 3145728;

  // 1. router path
  pool_part_k<<<dim3(Bn, 4), 256, 0, stream>>>(hidden, ppart);
  pool_final_k<<<dim3(32), 256, 0, stream>>>(ppart, pooled);
  router_k<<<1, 64, 0, stream>>>(pooled, router_w, router_b, probs, topi, wts, flags, out + OUT_COMBINED);

  // 2. bf16 conversions / transposes
  cvt_k<<<4096, 256, 0, stream>>>(hidden, hid_bf);
  bias3_k<<<4, 256, 0, stream>>>(bq, bk, bv, qkvbias);
  transpose_k<<<dim3(64, 16, Tn), 256, 0, stream>>>(W1, Wt, Hn, FFn, (long)Hn * FFn, (long)FFn * Hn, flags);
  transpose_k<<<dim3(16, 16, 1), 256, 0, stream>>>(Wq, wqt, Hn, Hn, 0, 0, nullptr);
  transpose_k<<<dim3(16, 16, 1), 256, 0, stream>>>(Wk, wkt, Hn, Hn, 0, 0, nullptr);
  transpose_k<<<dim3(16, 16, 1), 256, 0, stream>>>(Wv, wvt, Hn, Hn, 0, 0, nullptr);
  transpose_k<<<dim3(16, 16, 1), 256, 0, stream>>>(Wo, wot, Hn, Hn, 0, 0, nullptr);

  // 3. FFN1 (gelu) : per pair z: A=hid_bf[b], Bt=W1t[t], C=h[z]
  gemm_k<1, 0><<<dim3(FFn / 128, Sn / 128, 16), 256, 0, stream>>>(
      hid_bf, Wt, b1, hbuf, FFn, Hn, topi, 2,
      (long)Sn * Hn, 0L, (long)FFn * Hn, FFn, (long)Sn * FFn);

  // 4. W2 transpose reuses Wt region (W1t dead)
  transpose_k<<<dim3(16, 64, Tn), 256, 0, stream>>>(W2, Wt, FFn, Hn, (long)FFn * Hn, (long)Hn * FFn, flags);

  // 5. FFN2 : A=h[z], Bt=W2t[t], C=br[z]
  gemm_k<0, 0><<<dim3(Hn / 128, Sn / 128, 16), 256, 0, stream>>>(
      hbuf, Wt, b2, br, Hn, FFn, topi, 2,
      0L, (long)Sn * FFn, (long)Hn * FFn, Hn, (long)Sn * Hn);

  // 6. diversity from branch_out
  div_part_k<<<dim3(32, Bn), 256, 0, stream>>>(br, dpart);
  div_final_k<<<1, 64, 0, stream>>>(dpart, out + OUT_COMBINED + 1);

  // 7. fused QKV projection (N=3072; q/k normal, v transposed for flash)
  gemm_k<0, 1><<<dim3(3072 / 128, (Bn * Ln) / 128, 1), 256, 0, stream>>>(
      br, wqkvo, qkvbias, qb, 3072, Hn, nullptr, 0, 0L, 0L, 0L, 0, 0L);

  // 8. flash attention (128 q rows/block)
  flash_k<<<dim3(Ln / 128, NHn, Bn), 256, 0, stream>>>(qb, kbf, vt, ctx);

  // 9. output projection
  gemm_k<0, 0><<<dim3(Hn / 128, (Bn * Ln) / 128, 1), 256, 0, stream>>>(
      ctx, wot, bo, att, Hn, Hn, nullptr, 0, 0L, 0L, 0L, 0, 0L);

  // 10. weighted combine -> f32 output
  combine_k<<<2048, 256, 0, stream>>>(att, wts, out);
}

// Round 4
// 536.564 us; speedup vs baseline: 1.1692x; 1.0028x over previous
//
#include <hip/hip_runtime.h>
#include <hip/hip_bf16.h>
#include <math.h>

typedef float f32x4 __attribute__((ext_vector_type(4)));
typedef short s16x8 __attribute__((ext_vector_type(8)));
typedef short s16x4 __attribute__((ext_vector_type(4)));
typedef unsigned int u32;

#define DEVI __device__ __forceinline__

// ---- sizes ----
#define Bn   8
#define Sn   512
#define Hn   1024
#define Tn   8
#define Kn   2
#define FFn  4096
#define NHn  8
#define HDn  128
#define Ln   1024            // K*S
#define OUT_COMBINED 4194304 // B*S*H

DEVI unsigned short f2bf(float x) {
  __hip_bfloat16 h = __float2bfloat16(x);
  union { __hip_bfloat16 h; unsigned short u; } cv; cv.h = h; return cv.u;
}
DEVI float bf2f(unsigned short u) {
  union { u32 i; float f; } cv; cv.i = ((u32)u) << 16; return cv.f;
}

typedef __attribute__((address_space(3))) u32 lds_u32;
typedef __attribute__((address_space(1))) u32 glb_u32;
DEVI void gload16(const void* g, void* l) {
  __builtin_amdgcn_global_load_lds((const glb_u32*)g, (lds_u32*)l, 16, 0, 0);
}

// ---------------- pool (mean over S) ----------------
__global__ __launch_bounds__(256) void pool_part_k(const float* __restrict__ hid, float* __restrict__ part)
{
  const int b = blockIdx.x, scn = blockIdx.y;
  const int hh = threadIdx.x * 4;
  float4 acc = make_float4(0.f, 0.f, 0.f, 0.f);
  const float* base = hid + ((long)b * Sn + (long)scn * 128) * Hn + hh;
  for (int s = 0; s < 128; ++s) {
    float4 v = *(const float4*)(base + (long)s * Hn);
    acc.x += v.x; acc.y += v.y; acc.z += v.z; acc.w += v.w;
  }
  *(float4*)(part + ((long)(scn * Bn + b)) * Hn + hh) = acc;
}

__global__ __launch_bounds__(256) void pool_final_k(const float* __restrict__ part, float* __restrict__ pooled)
{
  const int i = blockIdx.x * 256 + threadIdx.x;
  float s = 0.f;
  for (int sc = 0; sc < 4; ++sc) s += part[sc * (Bn * Hn) + i];
  pooled[i] = s * (1.f / (float)Sn);
}

// ---------------- router + entropy (parallel dot: 256 threads) ----------------
__global__ __launch_bounds__(256) void router_k(
    const float* __restrict__ pooled, const float* __restrict__ rw, const float* __restrict__ rb,
    float* __restrict__ probs, int* __restrict__ topi, float* __restrict__ wts,
    int* __restrict__ flags, float* __restrict__ entropy_out)
{
  __shared__ float partial[256];
  __shared__ float lg[64];
  __shared__ int sfl[8];
  __shared__ float sent[8];
  const int tid = threadIdx.x;
  const int bt = tid & 63, slice = tid >> 6;
  const int b = bt >> 3, t = bt & 7;
  if (tid < 8) sfl[tid] = 0;
  float acc = 0.f;
  const float* pb = pooled + b * Hn;
  for (int i = slice * 256; i < slice * 256 + 256; ++i) acc += pb[i] * rw[i * Tn + t];
  partial[tid] = acc;
  __syncthreads();
  if (tid < 64) lg[tid] = rb[t] + partial[tid] + partial[tid + 64] + partial[tid + 128] + partial[tid + 192];
  __syncthreads();
  if (tid < 64 && t == 0) {
    float p[8];
    float mx = lg[b * 8];
    for (int i = 1; i < 8; ++i) mx = fmaxf(mx, lg[b * 8 + i]);
    float ssum = 0.f;
    for (int i = 0; i < 8; ++i) { p[i] = expf(lg[b * 8 + i] - mx); ssum += p[i]; }
    float ent = 0.f;
    for (int i = 0; i < 8; ++i) { p[i] /= ssum; ent -= p[i] * logf(p[i] + 1e-8f); probs[b * 8 + i] = p[i]; }
    sent[b] = ent;
    int i1 = 0;
    for (int i = 1; i < 8; ++i) if (p[i] > p[i1]) i1 = i;   // strict > : lowest index on ties (lax.top_k)
    int i2 = (i1 == 0) ? 1 : 0;
    for (int i = 0; i < 8; ++i) if (i != i1 && p[i] > p[i2]) i2 = i;
    float w0 = 1.f / (1.f + expf(p[i2] - p[i1]));
    float w1 = 1.f / (1.f + expf(p[i1] - p[i2]));
    topi[b * 2] = i1; topi[b * 2 + 1] = i2;
    wts[b * 2] = w0; wts[b * 2 + 1] = w1;
    atomicOr(&sfl[i1], 1); atomicOr(&sfl[i2], 1);
  }
  __syncthreads();
  if (tid < 8) flags[tid] = sfl[tid];
  if (tid == 0) {
    float e = 0.f;
    for (int i = 0; i < 8; ++i) e += sent[i];
    entropy_out[0] = e * (1.f / (float)Bn);
  }
}

// ---------------- f32 -> bf16 convert ----------------
__global__ __launch_bounds__(256) void cvt_k(const float* __restrict__ in, unsigned short* __restrict__ out)
{
  const long i = ((long)blockIdx.x * 256 + threadIdx.x) * 4;
  float4 v = *(const float4*)(in + i);
  s16x4 o;
  o[0] = (short)f2bf(v.x); o[1] = (short)f2bf(v.y); o[2] = (short)f2bf(v.z); o[3] = (short)f2bf(v.w);
  *(s16x4*)(out + i) = o;
}

// ---------------- bias concat for fused QKV ----------------
__global__ __launch_bounds__(256) void bias3_k(const float* __restrict__ bq, const float* __restrict__ bk,
                                               const float* __restrict__ bv, float* __restrict__ o)
{
  const int i = blockIdx.x * 256 + threadIdx.x;   // 0..1023
  o[i] = bq[i]; o[i + 1024] = bk[i]; o[i + 2048] = bv[i];
}

// ---------------- transpose+convert: in f32 [Kd][N] -> out bf16 [N][Kd], 64x64 tiles ----------------
__global__ __launch_bounds__(256) void transpose_k(const float* __restrict__ Win, unsigned short* __restrict__ Wout,
                                                   int Kd, int N, long sIn, long sOut, const int* __restrict__ flags)
{
  const int t = blockIdx.z;
  if (flags && flags[t] == 0) return;   // uniform per block
  __shared__ float tile[64][65];
  const float* in = Win + (long)t * sIn;
  unsigned short* out = Wout + (long)t * sOut;
  const int kb = blockIdx.y * 64, nb = blockIdx.x * 64;
  const int tx = threadIdx.x & 15, ty = threadIdx.x >> 4;
  #pragma unroll
  for (int i = 0; i < 4; ++i) {
    const int r = ty + i * 16;
    float4 v = *(const float4*)(in + (long)(kb + r) * N + nb + tx * 4);
    tile[r][tx * 4 + 0] = v.x; tile[r][tx * 4 + 1] = v.y;
    tile[r][tx * 4 + 2] = v.z; tile[r][tx * 4 + 3] = v.w;
  }
  __syncthreads();
  #pragma unroll
  for (int i = 0; i < 4; ++i) {
    const int n = ty + i * 16;
    s16x4 o;
    #pragma unroll
    for (int j = 0; j < 4; ++j) o[j] = (short)f2bf(tile[tx * 4 + j][n]);
    *(s16x4*)(out + (long)(nb + n) * Kd + kb + tx * 4) = o;
  }
}

// ---------------- GEMM 8-phase-class: C[M,N] = A[M,Kd] @ Bt[N,Kd]^T + bias ----------------
// BN=256 always. WM=2: BM=256, 512 thr, 8 waves, NBUF=4 (128KB LDS, 1 blk/CU).
//                WM=1: BM=128, 256 thr, 4 waves, NBUF=3 ( 72KB LDS, 2 blk/CU).
// Wave tile 128x64 (8 M-frag x 4 N-frag). BK=32. Per K-tile: 2 phases x 16 MFMA.
// Counted vmcnt (raw s_barrier, never __syncthreads in loop). T2 swizzle
// chunk ^= (row>>1)&3 via pre-swizzled GLOBAL source; linear LDS dest.
// EPI: 1 = exact gelu. OUTMODE 1 = fused QKV (q/k normal, v transposed).
template<int WM, int EPI, int OUTMODE>
__global__ __launch_bounds__(WM * 256, 2) void gemm256_k(
    const unsigned short* __restrict__ A0, const unsigned short* __restrict__ Bt0,
    const float* __restrict__ bias0, unsigned short* __restrict__ C0,
    int N, int Kd,
    const int* __restrict__ topi, int kTop,
    long sA_b, long sA_p, long sBt_t, int sBias_t, long sC_p)
{
  constexpr int NBUF = (WM == 2) ? 4 : 3;
  constexpr int ASZ = WM * 8192;     // bytes per A K-tile buffer (WM*128 rows x 64B)
  constexpr int BSZ = 16384;         // 256 rows x 64B
  constexpr int BISS = 4 / WM;       // B gload issues per K-tile (A is always 2)
  __shared__ __align__(16) char smem[NBUF * (ASZ + BSZ)];
  char* const Ab = smem;
  char* const Bb = smem + NBUF * ASZ;

  const int z = blockIdx.z;
  const int bidx = kTop ? (z / kTop) : 0;
  const int te = topi ? topi[z] : 0;
  const unsigned short* A = A0 + (long)bidx * sA_b + (long)z * sA_p;
  const unsigned short* Bt = Bt0 + (long)te * sBt_t;
  const float* bias = bias0 + (long)te * sBias_t;
  unsigned short* C = C0 + (long)z * sC_p;

  const int m0 = blockIdx.y * (WM * 128);
  const int n0 = blockIdx.x * 256;
  const int tid = threadIdx.x;
  const int lane = tid & 63, w = tid >> 6;
  const int wm = w >> 2, wn = w & 3;          // WM=1: wm=0
  const int rA = lane & 15, g = lane >> 4;

  // ---- staging sources (global pre-swizzled: chunk c ^ ((row>>1)&3)) ----
  const int srow = tid >> 2;                  // 0 .. WM*64-1
  const int sc   = tid & 3;
  const unsigned short* gA[2];
  #pragma unroll
  for (int i = 0; i < 2; ++i) {
    const int r = i * (WM * 64) + srow;
    gA[i] = A + (long)(m0 + r) * Kd + ((sc ^ ((r >> 1) & 3)) * 8);
  }
  const unsigned short* gB[BISS];
  #pragma unroll
  for (int i = 0; i < BISS; ++i) {
    const int r = i * (WM * 64) + srow;
    gB[i] = Bt + (long)(n0 + r) * Kd + ((sc ^ ((r >> 1) & 3)) * 8);
  }
  const int sdo = tid * 16;                   // linear LDS dest within issue block

  // ---- fragment LDS offsets (swizzled read) ----
  int aoff[8], boff[4];
  #pragma unroll
  for (int mi = 0; mi < 8; ++mi) {
    const int row = wm * 128 + mi * 16 + rA;
    aoff[mi] = row * 64 + ((g ^ ((row >> 1) & 3)) << 4);
  }
  #pragma unroll
  for (int nj = 0; nj < 4; ++nj) {
    const int row = wn * 64 + nj * 16 + rA;
    boff[nj] = row * 64 + ((g ^ ((row >> 1) & 3)) << 4);
  }

  f32x4 acc[8][4];
  const f32x4 zero = {0.f, 0.f, 0.f, 0.f};
  #pragma unroll
  for (int i = 0; i < 8; ++i)
    #pragma unroll
    for (int j = 0; j < 4; ++j) acc[i][j] = zero;

  const int nt = Kd >> 5;

  // ---- prologue: stage tiles 0..NBUF-2 ----
  for (int j = 0; j < NBUF - 1; ++j) {
    #pragma unroll
    for (int i = 0; i < 2; ++i)
      gload16(gA[i] + j * 32, Ab + j * ASZ + i * (WM * 4096) + sdo);
    #pragma unroll
    for (int i = 0; i < BISS; ++i)
      gload16(gB[i] + j * 32, Bb + j * BSZ + i * (WM * 4096) + sdo);
  }
  if constexpr (WM == 2) asm volatile("s_waitcnt vmcnt(8)" ::: "memory");
  else                   asm volatile("s_waitcnt vmcnt(6)" ::: "memory");
  __builtin_amdgcn_s_barrier();

  int cb = 0;
  for (int kt = 0; kt < nt; ++kt) {
    const char* pa = Ab + cb * ASZ;
    const char* pb = Bb + cb * BSZ;
    const int ft = kt + NBUF - 1;                      // future tile to stage
    const int fb = (cb == 0) ? NBUF - 1 : cb - 1;      // its buffer
    const bool st = (ft < nt);

    // ======== phase 0: A lower half + all B ========
    s16x8 af[4], bf[4];
    #pragma unroll
    for (int mi = 0; mi < 4; ++mi) af[mi] = *(const s16x8*)(pa + aoff[mi]);
    #pragma unroll
    for (int nj = 0; nj < 4; ++nj) bf[nj] = *(const s16x8*)(pb + boff[nj]);
    if (st) {
      #pragma unroll
      for (int i = 0; i < 2; ++i)
        gload16(gA[i] + ft * 32, Ab + fb * ASZ + i * (WM * 4096) + sdo);
      if constexpr (WM == 1)
        gload16(gB[0] + ft * 32, Bb + fb * BSZ + sdo);
    }
    asm volatile("" ::: "memory");
    __builtin_amdgcn_s_barrier();
    __builtin_amdgcn_s_setprio(1);
    #pragma unroll
    for (int mi = 0; mi < 4; ++mi)
      #pragma unroll
      for (int nj = 0; nj < 4; ++nj)
        acc[mi][nj] = __builtin_amdgcn_mfma_f32_16x16x32_bf16(af[mi], bf[nj], acc[mi][nj], 0, 0, 0);
    __builtin_amdgcn_s_setprio(0);
    __builtin_amdgcn_s_barrier();

    // ======== phase 1: A upper half (B reused) ========
    s16x8 af2[4];
    #pragma unroll
    for (int mi = 0; mi < 4; ++mi) af2[mi] = *(const s16x8*)(pa + aoff[4 + mi]);
    if (st) {
      if constexpr (WM == 2) {
        gload16(gB[0] + ft * 32, Bb + fb * BSZ + sdo);
        gload16(gB[1] + ft * 32, Bb + fb * BSZ + 8192 + sdo);
      } else {
        gload16(gB[1] + ft * 32, Bb + fb * BSZ + 4096 + sdo);
        gload16(gB[2] + ft * 32, Bb + fb * BSZ + 8192 + sdo);
        gload16(gB[3] + ft * 32, Bb + fb * BSZ + 12288 + sdo);
      }
    }
    asm volatile("" ::: "memory");
    __builtin_amdgcn_s_barrier();
    __builtin_amdgcn_s_setprio(1);
    #pragma unroll
    for (int mi = 0; mi < 4; ++mi)
      #pragma unroll
      for (int nj = 0; nj < 4; ++nj)
        acc[4 + mi][nj] = __builtin_amdgcn_mfma_f32_16x16x32_bf16(af2[mi], bf[nj], acc[4 + mi][nj], 0, 0, 0);
    __builtin_amdgcn_s_setprio(0);

    // ---- counted vmcnt at K-tile boundary: ensure tile kt+1 staged ----
    if constexpr (WM == 2) {
      if (kt < nt - 3)       asm volatile("s_waitcnt vmcnt(8)" ::: "memory");
      else if (kt == nt - 3) asm volatile("s_waitcnt vmcnt(4)" ::: "memory");
      else if (kt == nt - 2) asm volatile("s_waitcnt vmcnt(0)" ::: "memory");
    } else {
      if (kt < nt - 2)       asm volatile("s_waitcnt vmcnt(6)" ::: "memory");
      else if (kt == nt - 2) asm volatile("s_waitcnt vmcnt(0)" ::: "memory");
    }
    __builtin_amdgcn_s_barrier();
    cb = (cb + 1 == NBUF) ? 0 : cb + 1;
  }

  __syncthreads();   // safe drain before LDS reuse for epilogue

  // ---- epilogue via per-wave LDS tiles (two 64x64 parts, pitch 72 shorts) ----
  unsigned short* et = (unsigned short*)(smem + w * 9216);
  const int r4 = (lane >> 4) << 2;
  const int nbase = n0 + wn * 64;
  const int seg = (OUTMODE == 1) ? (nbase >> 10) : 0;
  const int erow = lane >> 3, echunk = lane & 7;
  float bv[4];
  #pragma unroll
  for (int nj = 0; nj < 4; ++nj) bv[nj] = bias[nbase + nj * 16 + rA];

  #pragma unroll
  for (int p = 0; p < 2; ++p) {
    #pragma unroll
    for (int nj = 0; nj < 4; ++nj) {
      #pragma unroll
      for (int mi2 = 0; mi2 < 4; ++mi2) {
        #pragma unroll
        for (int j = 0; j < 4; ++j) {
          float x = acc[p * 4 + mi2][nj][j] + bv[nj];
          if (EPI == 1) x = 0.5f * x * (1.0f + erff(x * 0.70710678118654752f));
          const int mrl = mi2 * 16 + r4 + j;
          const int ncl = nj * 16 + rA;
          if (OUTMODE == 0 || seg < 2) et[mrl * 72 + ncl] = f2bf(x);
          else                         et[ncl * 72 + mrl] = f2bf(x);
        }
      }
    }
    const long mrow0 = m0 + wm * 128 + p * 64;
    if (OUTMODE == 0) {
      #pragma unroll
      for (int rr = 0; rr < 8; ++rr) {
        const int row = rr * 8 + erow;
        s16x8 v = *(const s16x8*)(et + row * 72 + echunk * 8);
        *(s16x8*)(C + (mrow0 + row) * N + nbase + echunk * 8) = v;
      }
    } else {
      const int nseg = nbase & 1023;
      if (seg < 2) {
        unsigned short* dst = C + (long)seg * 8388608;
        #pragma unroll
        for (int rr = 0; rr < 8; ++rr) {
          const int row = rr * 8 + erow;
          s16x8 v = *(const s16x8*)(et + row * 72 + echunk * 8);
          *(s16x8*)(dst + (mrow0 + row) * 1024 + nseg + echunk * 8) = v;
        }
      } else {
        unsigned short* vtp = C + 16777216;
        const int bb = (int)(mrow0 >> 10);
        const int ltok0 = (int)(mrow0 & 1023);
        #pragma unroll
        for (int rr = 0; rr < 8; ++rr) {
          const int nrow = rr * 8 + erow;
          s16x8 v = *(const s16x8*)(et + nrow * 72 + echunk * 8);
          *(s16x8*)(vtp + ((long)(bb * 1024 + nseg + nrow)) * 1024 + ltok0 + echunk * 8) = v;
        }
      }
    }
  }
}

// ---------------- flash attention ----------------
// 128 q rows per block (4 waves x 32), KV tile 64, defer-max (m=0) + lane-local l.
// q,k: [B*L][H] bf16 ; vt: [B*NH*HD][L] bf16 ; ctx: [B*L][H] bf16
__global__ __launch_bounds__(256) void flash_k(
    const unsigned short* __restrict__ q, const unsigned short* __restrict__ k,
    const unsigned short* __restrict__ vt, unsigned short* __restrict__ ctx)
{
  __shared__ unsigned short Ks[64 * 128];    // [kv][hd], rows 256B, chunk^=(row&7)
  __shared__ unsigned short Vs[128 * 64];    // [hd][kv], rows 128B, chunk^=(row&7)
  __shared__ unsigned short Ps[4][32 * 72];  // per-wave P [32 q][64 kv], pitch 72 (144B)
  const int qt = blockIdx.x, h = blockIdx.y, b = blockIdx.z;
  const int tid = threadIdx.x, lane = tid & 63, w = tid >> 6;
  const int rA = lane & 15, g = lane >> 4;
  const int q0w = qt * 128 + w * 32;         // wave's 32 q rows

  s16x8 qf[2][4];
  #pragma unroll
  for (int qi = 0; qi < 2; ++qi) {
    const unsigned short* qp = q + ((long)(b * Ln + q0w + qi * 16 + rA)) * Hn + h * HDn + g * 8;
    #pragma unroll
    for (int kk = 0; kk < 4; ++kk) qf[qi][kk] = *(const s16x8*)(qp + kk * 32);
  }

  f32x4 o[2][8];
  const f32x4 zero = {0.f, 0.f, 0.f, 0.f};
  #pragma unroll
  for (int qi = 0; qi < 2; ++qi)
    #pragma unroll
    for (int nn = 0; nn < 8; ++nn) o[qi][nn] = zero;
  float lrun[2][4];
  #pragma unroll
  for (int qi = 0; qi < 2; ++qi)
    #pragma unroll
    for (int j = 0; j < 4; ++j) lrun[qi][j] = 0.f;
  float m = 0.f;

  const float sc2 = 0.08838834764831845f * 1.4426950408889634f;  // 1/sqrt(128)*log2(e)

  const int krow0 = w * 16 + g;
  const int kc = lane & 15;
  const int vrow0 = w * 32 + (lane >> 3);
  const int vc = lane & 7;

  for (int kvt = 0; kvt < 16; ++kvt) {
    const int kv0 = kvt * 64;
    __syncthreads();
    #pragma unroll
    for (int qq = 0; qq < 4; ++qq) {
      const int rk = krow0 + qq * 4;
      gload16(k + ((long)(b * Ln + kv0 + rk)) * Hn + h * HDn + ((kc ^ (rk & 7)) * 8),
              (char*)Ks + w * 4096 + qq * 1024);
      const int rv = vrow0 + qq * 8;
      gload16(vt + ((long)(b * 1024 + h * HDn + rv)) * Ln + kv0 + ((vc ^ (rv & 7)) * 8),
              (char*)Vs + w * 4096 + qq * 1024);
    }
    __syncthreads();

    f32x4 sacc[2][4];
    #pragma unroll
    for (int qi = 0; qi < 2; ++qi)
      #pragma unroll
      for (int nj = 0; nj < 4; ++nj) sacc[qi][nj] = zero;
    #pragma unroll
    for (int kk = 0; kk < 4; ++kk) {
      #pragma unroll
      for (int nj = 0; nj < 4; ++nj) {
        const int row = nj * 16 + rA;
        const int byt = row * 256 + (((kk * 4 + g) ^ (row & 7)) << 4);
        s16x8 kf = *(const s16x8*)((const char*)Ks + byt);
        sacc[0][nj] = __builtin_amdgcn_mfma_f32_16x16x32_bf16(qf[0][kk], kf, sacc[0][nj], 0, 0, 0);
        sacc[1][nj] = __builtin_amdgcn_mfma_f32_16x16x32_bf16(qf[1][kk], kf, sacc[1][nj], 0, 0, 0);
      }
    }

    float vmax = -3.0e38f;
    #pragma unroll
    for (int qi = 0; qi < 2; ++qi)
      #pragma unroll
      for (int nj = 0; nj < 4; ++nj)
        #pragma unroll
        for (int j = 0; j < 4; ++j) {
          const float s = sacc[qi][nj][j] * sc2;
          sacc[qi][nj][j] = s;
          vmax = fmaxf(vmax, s);
        }
    if (!__all(vmax <= m + 8.0f)) {
      float mn = vmax;
      #pragma unroll
      for (int mm = 1; mm < 64; mm <<= 1) mn = fmaxf(mn, __shfl_xor(mn, mm, 64));
      const float al = exp2f(m - mn);
      #pragma unroll
      for (int qi = 0; qi < 2; ++qi) {
        #pragma unroll
        for (int nn = 0; nn < 8; ++nn)
          #pragma unroll
          for (int j = 0; j < 4; ++j) o[qi][nn][j] *= al;
        #pragma unroll
        for (int j = 0; j < 4; ++j) lrun[qi][j] *= al;
      }
      m = mn;
    }
    #pragma unroll
    for (int qi = 0; qi < 2; ++qi)
      #pragma unroll
      for (int j = 0; j < 4; ++j) {
        float p0 = exp2f(sacc[qi][0][j] - m);
        float p1 = exp2f(sacc[qi][1][j] - m);
        float p2 = exp2f(sacc[qi][2][j] - m);
        float p3 = exp2f(sacc[qi][3][j] - m);
        lrun[qi][j] += (p0 + p1) + (p2 + p3);
        const int prow = (qi * 16 + g * 4 + j) * 72;
        Ps[w][prow + 0 * 16 + rA] = f2bf(p0);
        Ps[w][prow + 1 * 16 + rA] = f2bf(p1);
        Ps[w][prow + 2 * 16 + rA] = f2bf(p2);
        Ps[w][prow + 3 * 16 + rA] = f2bf(p3);
      }

    s16x8 pf[2][2];
    #pragma unroll
    for (int qi = 0; qi < 2; ++qi)
      #pragma unroll
      for (int kk2 = 0; kk2 < 2; ++kk2)
        pf[qi][kk2] = *(const s16x8*)(&Ps[w][(qi * 16 + rA) * 72 + kk2 * 32 + g * 8]);
    #pragma unroll
    for (int kk2 = 0; kk2 < 2; ++kk2) {
      #pragma unroll
      for (int nn = 0; nn < 8; ++nn) {
        const int row = nn * 16 + rA;
        const int byt = row * 128 + (((kk2 * 4 + g) ^ (row & 7)) << 4);
        s16x8 vf = *(const s16x8*)((const char*)Vs + byt);
        o[0][nn] = __builtin_amdgcn_mfma_f32_16x16x32_bf16(pf[0][kk2], vf, o[0][nn], 0, 0, 0);
        o[1][nn] = __builtin_amdgcn_mfma_f32_16x16x32_bf16(pf[1][kk2], vf, o[1][nn], 0, 0, 0);
      }
    }
  }

  float linv[2][4];
  #pragma unroll
  for (int qi = 0; qi < 2; ++qi)
    #pragma unroll
    for (int j = 0; j < 4; ++j) {
      float l = lrun[qi][j];
      #pragma unroll
      for (int mm = 1; mm < 16; mm <<= 1) l += __shfl_xor(l, mm, 64);
      linv[qi][j] = 1.0f / l;
    }
  #pragma unroll
  for (int qi = 0; qi < 2; ++qi)
    #pragma unroll
    for (int nn = 0; nn < 8; ++nn)
      #pragma unroll
      for (int j = 0; j < 4; ++j) {
        const int row = q0w + qi * 16 + g * 4 + j;
        ctx[((long)(b * Ln + row)) * Hn + h * HDn + nn * 16 + rA] = f2bf(o[qi][nn][j] * linv[qi][j]);
      }
}

// ---------------- diversity ----------------
__global__ __launch_bounds__(256) void div_part_k(const unsigned short* __restrict__ br, float* __restrict__ part)
{
  const int b = blockIdx.y, ch = blockIdx.x;
  const unsigned short* a = br + (long)b * (2L * Sn * Hn);
  const unsigned short* c = a + (long)Sn * Hn;
  const int base = ch * 16384 + threadIdx.x * 8;
  float dot = 0.f, na = 0.f, nb = 0.f;
  #pragma unroll
  for (int i = 0; i < 8; ++i) {
    const int idx = base + i * 2048;
    s16x8 av = *(const s16x8*)(a + idx);
    s16x8 cv = *(const s16x8*)(c + idx);
    #pragma unroll
    for (int e = 0; e < 8; ++e) {
      float fa = bf2f((unsigned short)av[e]);
      float fc = bf2f((unsigned short)cv[e]);
      dot += fa * fc; na += fa * fa; nb += fc * fc;
    }
  }
  #pragma unroll
  for (int mm = 1; mm < 64; mm <<= 1) {
    dot += __shfl_xor(dot, mm, 64);
    na  += __shfl_xor(na, mm, 64);
    nb  += __shfl_xor(nb, mm, 64);
  }
  __shared__ float red[12];
  const int lane = threadIdx.x & 63, w = threadIdx.x >> 6;
  if (lane == 0) { red[w * 3] = dot; red[w * 3 + 1] = na; red[w * 3 + 2] = nb; }
  __syncthreads();
  if (threadIdx.x == 0) {
    float d = 0, x = 0, y = 0;
    for (int i = 0; i < 4; ++i) { d += red[i * 3]; x += red[i * 3 + 1]; y += red[i * 3 + 2]; }
    float* op = part + ((long)(b * 32 + ch)) * 3;
    op[0] = d; op[1] = x; op[2] = y;
  }
}

__global__ __launch_bounds__(64) void div_final_k(const float* __restrict__ part, float* __restrict__ outp)
{
  __shared__ float cosr[8];
  const int tid = threadIdx.x;
  if (tid < 8) {
    float d = 0, x = 0, y = 0;
    for (int i = 0; i < 32; ++i) {
      const float* p = part + ((long)(tid * 32 + i)) * 3;
      d += p[0]; x += p[1]; y += p[2];
    }
    cosr[tid] = d / fmaxf(sqrtf(x) * sqrtf(y), 1e-8f);
  }
  __syncthreads();
  if (tid == 0) {
    float s = 0.f;
    for (int i = 0; i < 8; ++i) s += 1.f - cosr[i];
    outp[0] = s * (1.f / 8.f);
  }
}

// ---------------- weighted combine ----------------
__global__ __launch_bounds__(256) void combine_k(const unsigned short* __restrict__ att,
                                                 const float* __restrict__ wts, float* __restrict__ out)
{
  const long i = ((long)blockIdx.x * 256 + threadIdx.x) * 8;
  const int b = (int)(i >> 19);           // S*H = 524288
  const long rem = i & 524287;
  const unsigned short* a0 = att + (long)b * (2L * Sn * Hn) + rem;
  const unsigned short* a1 = a0 + (long)Sn * Hn;
  const float w0 = wts[b * 2], w1 = wts[b * 2 + 1];
  s16x8 v0 = *(const s16x8*)a0;
  s16x8 v1 = *(const s16x8*)a1;
  float r[8];
  #pragma unroll
  for (int e = 0; e < 8; ++e) r[e] = w0 * bf2f((unsigned short)v0[e]) + w1 * bf2f((unsigned short)v1[e]);
  *(float4*)(out + i)     = make_float4(r[0], r[1], r[2], r[3]);
  *(float4*)(out + i + 4) = make_float4(r[4], r[5], r[6], r[7]);
}

// ---------------- launch ----------------
extern "C" void kernel_launch(void* const* d_in, const int* in_sizes, int n_in,
                              void* d_out, int out_size, void* d_ws, size_t ws_size,
                              hipStream_t stream)
{
  (void)in_sizes; (void)n_in; (void)out_size; (void)ws_size;
  const float* hidden   = (const float*)d_in[0];
  const float* router_w = (const float*)d_in[1];
  const float* router_b = (const float*)d_in[2];
  const float* W1 = (const float*)d_in[3];
  const float* b1 = (const float*)d_in[4];
  const float* W2 = (const float*)d_in[5];
  const float* b2 = (const float*)d_in[6];
  const float* Wq = (const float*)d_in[7];
  const float* bq = (const float*)d_in[8];
  const float* Wk = (const float*)d_in[9];
  const float* bk = (const float*)d_in[10];
  const float* Wv = (const float*)d_in[11];
  const float* bv = (const float*)d_in[12];
  const float* Wo = (const float*)d_in[13];
  const float* bo = (const float*)d_in[14];
  float* out = (float*)d_out;

  char* ws = (char*)d_ws;
  float* pooled  = (float*)(ws);                    // 32KB
  float* ppart   = (float*)(ws + 32768);            // 128KB
  float* probs   = (float*)(ws + 163840);
  int*   topi    = (int*)  (ws + 164096);
  float* wts     = (float*)(ws + 164352);
  int*   flags   = (int*)  (ws + 164608);
  float* dpart   = (float*)(ws + 164864);           // 3KB
  float* qkvbias = (float*)(ws + 167936);           // 12KB
  unsigned short* hid_bf = (unsigned short*)(ws + 262144);                           // 8.39MB
  unsigned short* Wt     = (unsigned short*)(ws + 262144 + 8388608);                 // 67.1MB: W1t -> W2t -> q/k/vt
  unsigned short* hbuf   = (unsigned short*)(ws + 262144 + 8388608 + 67108864);      // 67.1MB: h -> ctx/att
  unsigned short* br     = (unsigned short*)(ws + 262144 + 8388608 + 134217728);     // 16.8MB
  unsigned short* wqkvo  = (unsigned short*)(ws + 262144 + 8388608 + 134217728 + 16777216); // 8.4MB
  unsigned short* qb  = Wt;
  unsigned short* kbf = Wt + 8388608;
  unsigned short* vt  = Wt + 16777216;
  unsigned short* ctx = hbuf;
  unsigned short* att = hbuf + 8388608;
  unsigned short* wqt = wqkvo;
  unsigned short* wkt = wqkvo + 1048576;
  unsigned short* wvt = wqkvo + 2097152;
  unsigned short* wot = wqkvo + 3145728;

  // 1. router path
  pool_part_k<<<dim3(Bn, 4), 256, 0, stream>>>(hidden, ppart);
  pool_final_k<<<dim3(32), 256, 0, stream>>>(ppart, pooled);
  router_k<<<1, 256, 0, stream>>>(pooled, router_w, router_b, probs, topi, wts, flags, out + OUT_COMBINED);

  // 2. bf16 conversions / transposes
  cvt_k<<<4096, 256, 0, stream>>>(hidden, hid_bf);
  bias3_k<<<4, 256, 0, stream>>>(bq, bk, bv, qkvbias);
  transpose_k<<<dim3(64, 16, Tn), 256, 0, stream>>>(W1, Wt, Hn, FFn, (long)Hn * FFn, (long)FFn * Hn, flags);
  transpose_k<<<dim3(16, 16, 1), 256, 0, stream>>>(Wq, wqt, Hn, Hn, 0, 0, nullptr);
  transpose_k<<<dim3(16, 16, 1), 256, 0, stream>>>(Wk, wkt, Hn, Hn, 0, 0, nullptr);
  transpose_k<<<dim3(16, 16, 1), 256, 0, stream>>>(Wv, wvt, Hn, Hn, 0, 0, nullptr);
  transpose_k<<<dim3(16, 16, 1), 256, 0, stream>>>(Wo, wot, Hn, Hn, 0, 0, nullptr);

  // 3. FFN1 (gelu): WM=2, grid (16,2,16)=512 blocks
  gemm256_k<2, 1, 0><<<dim3(FFn / 256, Sn / 256, 16), 512, 0, stream>>>(
      hid_bf, Wt, b1, hbuf, FFn, Hn, topi, 2,
      (long)Sn * Hn, 0L, (long)FFn * Hn, FFn, (long)Sn * FFn);

  // 4. W2 transpose reuses Wt region (W1t dead)
  transpose_k<<<dim3(16, 64, Tn), 256, 0, stream>>>(W2, Wt, FFn, Hn, (long)FFn * Hn, (long)Hn * FFn, flags);

  // 5. FFN2: WM=1, grid (4,4,16)=256 blocks
  gemm256_k<1, 0, 0><<<dim3(Hn / 256, Sn / 128, 16), 256, 0, stream>>>(
      hbuf, Wt, b2, br, Hn, FFn, topi, 2,
      0L, (long)Sn * FFn, (long)Hn * FFn, Hn, (long)Sn * Hn);

  // 6. diversity from branch_out
  div_part_k<<<dim3(32, Bn), 256, 0, stream>>>(br, dpart);
  div_final_k<<<1, 64, 0, stream>>>(dpart, out + OUT_COMBINED + 1);

  // 7. fused QKV projection: WM=2, grid (12,32)=384 blocks
  gemm256_k<2, 0, 1><<<dim3(3072 / 256, (Bn * Ln) / 256, 1), 512, 0, stream>>>(
      br, wqkvo, qkvbias, qb, 3072, Hn, nullptr, 0, 0L, 0L, 0L, 0, 0L);

  // 8. flash attention (128 q rows/block)
  flash_k<<<dim3(Ln / 128, NHn, Bn), 256, 0, stream>>>(qb, kbf, vt, ctx);

  // 9. output projection: WM=1, grid (4,64)=256 blocks
  gemm256_k<1, 0, 0><<<dim3(Hn / 256, (Bn * Ln) / 128, 1), 256, 0, stream>>>(
      ctx, wot, bo, att, Hn, Hn, nullptr, 0, 0L, 0L, 0L, 0, 0L);

  // 10. weighted combine -> f32 output
  combine_k<<<2048, 256, 0, stream>>>(att, wts, out);
}

// Round 5
// 523.937 us; speedup vs baseline: 1.1973x; 1.0241x over previous
//
#include <hip/hip_runtime.h>
#include <hip/hip_bf16.h>
#include <math.h>

typedef float f32x4 __attribute__((ext_vector_type(4)));
typedef short s16x8 __attribute__((ext_vector_type(8)));
typedef short s16x4 __attribute__((ext_vector_type(4)));
typedef unsigned int u32;

#define DEVI __device__ __forceinline__

// ---- sizes ----
#define Bn   8
#define Sn   512
#define Hn   1024
#define Tn   8
#define Kn   2
#define FFn  4096
#define NHn  8
#define HDn  128
#define Ln   1024            // K*S
#define OUT_COMBINED 4194304 // B*S*H

DEVI unsigned short f2bf(float x) {
  __hip_bfloat16 h = __float2bfloat16(x);
  union { __hip_bfloat16 h; unsigned short u; } cv; cv.h = h; return cv.u;
}
DEVI float bf2f(unsigned short u) {
  union { u32 i; float f; } cv; cv.i = ((u32)u) << 16; return cv.f;
}
// tanh-form GELU: |err| vs exact erf-GELU < 1e-3 (bf16 eps dominates)
DEVI float gelu_f(float x) {
  float t = x * x * x;
  float y = 0.7978845608028654f * x + 0.03567740813f * t;
  float e = exp2f(2.8853900817779268f * y);      // e^{2y}
  return x - x / (e + 1.0f);                      // x * e/(e+1)
}

typedef __attribute__((address_space(3))) u32 lds_u32;
typedef __attribute__((address_space(1))) u32 glb_u32;
DEVI void gload16(const void* g, void* l) {
  __builtin_amdgcn_global_load_lds((const glb_u32*)g, (lds_u32*)l, 16, 0, 0);
}

// ---------------- pool (mean over S) ----------------
__global__ __launch_bounds__(256) void pool_part_k(const float* __restrict__ hid, float* __restrict__ part)
{
  const int b = blockIdx.x, scn = blockIdx.y;
  const int hh = threadIdx.x * 4;
  float4 acc = make_float4(0.f, 0.f, 0.f, 0.f);
  const float* base = hid + ((long)b * Sn + (long)scn * 128) * Hn + hh;
  for (int s = 0; s < 128; ++s) {
    float4 v = *(const float4*)(base + (long)s * Hn);
    acc.x += v.x; acc.y += v.y; acc.z += v.z; acc.w += v.w;
  }
  *(float4*)(part + ((long)(scn * Bn + b)) * Hn + hh) = acc;
}

__global__ __launch_bounds__(256) void pool_final_k(const float* __restrict__ part, float* __restrict__ pooled)
{
  const int i = blockIdx.x * 256 + threadIdx.x;
  float s = 0.f;
  for (int sc = 0; sc < 4; ++sc) s += part[sc * (Bn * Hn) + i];
  pooled[i] = s * (1.f / (float)Sn);
}

// ---------------- router + entropy (parallel dot: 256 threads) ----------------
__global__ __launch_bounds__(256) void router_k(
    const float* __restrict__ pooled, const float* __restrict__ rw, const float* __restrict__ rb,
    float* __restrict__ probs, int* __restrict__ topi, float* __restrict__ wts,
    int* __restrict__ flags, float* __restrict__ entropy_out)
{
  __shared__ float partial[256];
  __shared__ float lg[64];
  __shared__ int sfl[8];
  __shared__ float sent[8];
  const int tid = threadIdx.x;
  const int bt = tid & 63, slice = tid >> 6;
  const int b = bt >> 3, t = bt & 7;
  if (tid < 8) sfl[tid] = 0;
  float acc = 0.f;
  const float* pb = pooled + b * Hn;
  for (int i = slice * 256; i < slice * 256 + 256; ++i) acc += pb[i] * rw[i * Tn + t];
  partial[tid] = acc;
  __syncthreads();
  if (tid < 64) lg[tid] = rb[t] + partial[tid] + partial[tid + 64] + partial[tid + 128] + partial[tid + 192];
  __syncthreads();
  if (tid < 64 && t == 0) {
    float p[8];
    float mx = lg[b * 8];
    for (int i = 1; i < 8; ++i) mx = fmaxf(mx, lg[b * 8 + i]);
    float ssum = 0.f;
    for (int i = 0; i < 8; ++i) { p[i] = expf(lg[b * 8 + i] - mx); ssum += p[i]; }
    float ent = 0.f;
    for (int i = 0; i < 8; ++i) { p[i] /= ssum; ent -= p[i] * logf(p[i] + 1e-8f); probs[b * 8 + i] = p[i]; }
    sent[b] = ent;
    int i1 = 0;
    for (int i = 1; i < 8; ++i) if (p[i] > p[i1]) i1 = i;   // strict > : lowest index on ties (lax.top_k)
    int i2 = (i1 == 0) ? 1 : 0;
    for (int i = 0; i < 8; ++i) if (i != i1 && p[i] > p[i2]) i2 = i;
    float w0 = 1.f / (1.f + expf(p[i2] - p[i1]));
    float w1 = 1.f / (1.f + expf(p[i1] - p[i2]));
    topi[b * 2] = i1; topi[b * 2 + 1] = i2;
    wts[b * 2] = w0; wts[b * 2 + 1] = w1;
    atomicOr(&sfl[i1], 1); atomicOr(&sfl[i2], 1);
  }
  __syncthreads();
  if (tid < 8) flags[tid] = sfl[tid];
  if (tid == 0) {
    float e = 0.f;
    for (int i = 0; i < 8; ++i) e += sent[i];
    entropy_out[0] = e * (1.f / (float)Bn);
  }
}

// ---------------- f32 -> bf16 convert ----------------
__global__ __launch_bounds__(256) void cvt_k(const float* __restrict__ in, unsigned short* __restrict__ out)
{
  const long i = ((long)blockIdx.x * 256 + threadIdx.x) * 4;
  float4 v = *(const float4*)(in + i);
  s16x4 o;
  o[0] = (short)f2bf(v.x); o[1] = (short)f2bf(v.y); o[2] = (short)f2bf(v.z); o[3] = (short)f2bf(v.w);
  *(s16x4*)(out + i) = o;
}

// ---------------- bias concat for fused QKV ----------------
__global__ __launch_bounds__(256) void bias3_k(const float* __restrict__ bq, const float* __restrict__ bk,
                                               const float* __restrict__ bv, float* __restrict__ o)
{
  const int i = blockIdx.x * 256 + threadIdx.x;   // 0..1023
  o[i] = bq[i]; o[i + 1024] = bk[i]; o[i + 2048] = bv[i];
}

// ---------------- transpose+convert: in f32 [Kd][N] -> out bf16 [N][Kd], 64x64 tiles ----------------
__global__ __launch_bounds__(256) void transpose_k(const float* __restrict__ Win, unsigned short* __restrict__ Wout,
                                                   int Kd, int N, long sIn, long sOut, const int* __restrict__ flags)
{
  const int t = blockIdx.z;
  if (flags && flags[t] == 0) return;   // uniform per block
  __shared__ float tile[64][65];
  const float* in = Win + (long)t * sIn;
  unsigned short* out = Wout + (long)t * sOut;
  const int kb = blockIdx.y * 64, nb = blockIdx.x * 64;
  const int tx = threadIdx.x & 15, ty = threadIdx.x >> 4;
  #pragma unroll
  for (int i = 0; i < 4; ++i) {
    const int r = ty + i * 16;
    float4 v = *(const float4*)(in + (long)(kb + r) * N + nb + tx * 4);
    tile[r][tx * 4 + 0] = v.x; tile[r][tx * 4 + 1] = v.y;
    tile[r][tx * 4 + 2] = v.z; tile[r][tx * 4 + 3] = v.w;
  }
  __syncthreads();
  #pragma unroll
  for (int i = 0; i < 4; ++i) {
    const int n = ty + i * 16;
    s16x4 o;
    #pragma unroll
    for (int j = 0; j < 4; ++j) o[j] = (short)f2bf(tile[tx * 4 + j][n]);
    *(s16x4*)(out + (long)(nb + n) * Kd + kb + tx * 4) = o;
  }
}

// ---------------- GEMM: C[M,N] = A[M,Kd] @ Bt[N,Kd]^T + bias ----------------
// BM=256, BN=128, BK=32. 4 waves (2M x 2N), wave tile 128x64. NBUF=3 (72KB LDS)
// -> 2 blocks/CU: each SIMD carries 2 waves from INDEPENDENT blocks so one
// block's LDS/barrier window overlaps the other's MFMA (m114 co-schedule).
// Counted boundary vmcnt(6): 6 gload issues/wave/K-tile, staged 2 tiles ahead,
// so vmcnt(6) at a boundary proves tile kt+1 fully landed. Never drains in-loop.
// Swizzle: chunk ^= (row&3)^((row>>2)&3) via pre-swizzled GLOBAL source (dest linear).
// T1: bijective XCD remap of tile ids (consecutive N-tiles share A-strip -> same XCD L2).
// EPI: 1 = tanh-GELU. OUTMODE 1 = fused QKV (q/k normal, v transposed).
template<int EPI, int OUTMODE>
__global__ __launch_bounds__(256, 2) void gemmT_k(
    const unsigned short* __restrict__ A0, const unsigned short* __restrict__ Bt0,
    const float* __restrict__ bias0, unsigned short* __restrict__ C0,
    int N, int Kd,
    const int* __restrict__ topi, int kTop,
    long sA_b, long sA_p, long sBt_t, int sBias_t, long sC_p)
{
  __shared__ __align__(16) char smem[73728];
  char* const Ab = smem;              // 3 x 16384 (256 rows x 64B)
  char* const Bb = smem + 49152;      // 3 x  8192 (128 rows x 64B)

  // ---- T1 bijective XCD tile remap ----
  const int gx = gridDim.x, gy = gridDim.y;
  const int nwg = gx * gy * gridDim.z;
  const int hw = blockIdx.x + gx * (blockIdx.y + gy * blockIdx.z);
  const int q = nwg >> 3, r = nwg & 7;
  const int xcd = hw & 7, sub = hw >> 3;
  int lin = (xcd < r ? xcd * (q + 1) : r * (q + 1) + (xcd - r) * q) + sub;
  const int bx = lin % gx; lin /= gx;
  const int by = lin % gy;
  const int bz = lin / gy;

  const int bidx = kTop ? (bz / kTop) : 0;
  const int te = topi ? topi[bz] : 0;
  const unsigned short* A = A0 + (long)bidx * sA_b + (long)bz * sA_p;
  const unsigned short* Bt = Bt0 + (long)te * sBt_t;
  const float* bias = bias0 + (long)te * sBias_t;
  unsigned short* C = C0 + (long)bz * sC_p;

  const int m0 = by * 256;
  const int n0 = bx * 128;
  const int tid = threadIdx.x;
  const int lane = tid & 63, w = tid >> 6;
  const int wm = w >> 1, wn = w & 1;
  const int rA = lane & 15, g = lane >> 4;

  // ---- staging sources (pre-swizzled global chunk) ----
  const int sr = lane >> 2;                 // 0..15 (row within 16-row issue block)
  const int sc = lane & 3;                  // chunk
  const int csw = (sc ^ ((sr & 3) ^ ((sr >> 2) & 3))) * 8;   // bf16-elem offset
  const unsigned short* gAw = A + (long)(m0 + w * 64 + sr) * Kd + csw;  // + i*16*Kd + kt*32
  const unsigned short* gBw = Bt + (long)(n0 + w * 32 + sr) * Kd + csw;
  const int ldso = lane << 4;

  // ---- fragment LDS byte offsets (swizzled read) ----
  const int sl = (rA & 3) ^ ((rA >> 2) & 3);
  int aoff[8], boff[4];
  #pragma unroll
  for (int mi = 0; mi < 8; ++mi)
    aoff[mi] = (wm * 128 + mi * 16 + rA) * 64 + ((g ^ sl) << 4);
  #pragma unroll
  for (int nj = 0; nj < 4; ++nj)
    boff[nj] = (wn * 64 + nj * 16 + rA) * 64 + ((g ^ sl) << 4);

  f32x4 acc[8][4];
  const f32x4 zero = {0.f, 0.f, 0.f, 0.f};
  #pragma unroll
  for (int i = 0; i < 8; ++i)
    #pragma unroll
    for (int j = 0; j < 4; ++j) acc[i][j] = zero;

  const int nt = Kd >> 5;

  auto stageA = [&](int kt2, int buf, int i) {
    gload16(gAw + (long)i * 16 * Kd + kt2 * 32, Ab + buf * 16384 + w * 4096 + i * 1024 + ldso);
  };
  auto stageB = [&](int kt2, int buf, int i) {
    gload16(gBw + (long)i * 16 * Kd + kt2 * 32, Bb + buf * 8192 + w * 2048 + i * 1024 + ldso);
  };

  // ---- prologue: stage tiles 0,1 (6 issues each, in order) ----
  #pragma unroll
  for (int j = 0; j < 2; ++j) {
    stageA(j, j, 0); stageA(j, j, 1); stageB(j, j, 0);
    stageA(j, j, 2); stageA(j, j, 3); stageB(j, j, 1);
  }
  asm volatile("s_waitcnt vmcnt(6)" ::: "memory");   // tile 0 landed
  __builtin_amdgcn_s_barrier();

  int cb = 0, fb = 2;
  for (int kt = 0; kt < nt; ++kt) {
    const char* pa = Ab + cb * 16384;
    const char* pb = Bb + cb * 8192;
    const bool st = (kt + 2 < nt);
    const int ft = kt + 2;

    // ======== phase 0: mi 0-3 (B read once, reused in phase 1) ========
    s16x8 af[4], bf[4];
    #pragma unroll
    for (int mi = 0; mi < 4; ++mi) af[mi] = *(const s16x8*)(pa + aoff[mi]);
    #pragma unroll
    for (int nj = 0; nj < 4; ++nj) bf[nj] = *(const s16x8*)(pb + boff[nj]);
    if (st) { stageA(ft, fb, 0); stageA(ft, fb, 1); stageB(ft, fb, 0); }
    asm volatile("" ::: "memory");
    __builtin_amdgcn_s_barrier();
    __builtin_amdgcn_s_setprio(1);
    #pragma unroll
    for (int mi = 0; mi < 4; ++mi)
      #pragma unroll
      for (int nj = 0; nj < 4; ++nj)
        acc[mi][nj] = __builtin_amdgcn_mfma_f32_16x16x32_bf16(af[mi], bf[nj], acc[mi][nj], 0, 0, 0);
    __builtin_amdgcn_s_setprio(0);

    // ======== phase 1: mi 4-7 ========
    s16x8 af2[4];
    #pragma unroll
    for (int mi = 0; mi < 4; ++mi) af2[mi] = *(const s16x8*)(pa + aoff[4 + mi]);
    if (st) { stageA(ft, fb, 2); stageA(ft, fb, 3); stageB(ft, fb, 1); }
    asm volatile("" ::: "memory");
    __builtin_amdgcn_s_barrier();
    __builtin_amdgcn_s_setprio(1);
    #pragma unroll
    for (int mi = 0; mi < 4; ++mi)
      #pragma unroll
      for (int nj = 0; nj < 4; ++nj)
        acc[4 + mi][nj] = __builtin_amdgcn_mfma_f32_16x16x32_bf16(af2[mi], bf[nj], acc[4 + mi][nj], 0, 0, 0);
    __builtin_amdgcn_s_setprio(0);

    // ---- K-tile boundary: counted wait proves tile kt+1 is resident ----
    if (st)                asm volatile("s_waitcnt vmcnt(6)" ::: "memory");
    else if (kt + 1 < nt)  asm volatile("s_waitcnt vmcnt(0)" ::: "memory");
    __builtin_amdgcn_s_barrier();
    cb = (cb + 1 == 3) ? 0 : cb + 1;
    fb = (fb + 1 == 3) ? 0 : fb + 1;
  }

  __syncthreads();   // drain before LDS reuse for epilogue

  // ---- epilogue via per-wave LDS tiles (two 64x64 parts, pitch 72 shorts) ----
  unsigned short* et = (unsigned short*)(smem + w * 9216);
  const int r4 = (lane >> 4) << 2;
  const int nbase = n0 + wn * 64;
  const int seg = (OUTMODE == 1) ? (nbase >> 10) : 0;
  const int erow = lane >> 3, echunk = lane & 7;
  float bv[4];
  #pragma unroll
  for (int nj = 0; nj < 4; ++nj) bv[nj] = bias[nbase + nj * 16 + rA];

  #pragma unroll
  for (int p = 0; p < 2; ++p) {
    #pragma unroll
    for (int nj = 0; nj < 4; ++nj) {
      #pragma unroll
      for (int mi2 = 0; mi2 < 4; ++mi2) {
        #pragma unroll
        for (int j = 0; j < 4; ++j) {
          float x = acc[p * 4 + mi2][nj][j] + bv[nj];
          if (EPI == 1) x = gelu_f(x);
          const int mrl = mi2 * 16 + r4 + j;
          const int ncl = nj * 16 + rA;
          if (OUTMODE == 0 || seg < 2) et[mrl * 72 + ncl] = f2bf(x);
          else                         et[ncl * 72 + mrl] = f2bf(x);
        }
      }
    }
    const long mrow0 = m0 + wm * 128 + p * 64;
    if (OUTMODE == 0) {
      #pragma unroll
      for (int rr = 0; rr < 8; ++rr) {
        const int row = rr * 8 + erow;
        s16x8 v = *(const s16x8*)(et + row * 72 + echunk * 8);
        *(s16x8*)(C + (mrow0 + row) * N + nbase + echunk * 8) = v;
      }
    } else {
      const int nseg = nbase & 1023;
      if (seg < 2) {
        unsigned short* dst = C + (long)seg * 8388608;
        #pragma unroll
        for (int rr = 0; rr < 8; ++rr) {
          const int row = rr * 8 + erow;
          s16x8 v = *(const s16x8*)(et + row * 72 + echunk * 8);
          *(s16x8*)(dst + (mrow0 + row) * 1024 + nseg + echunk * 8) = v;
        }
      } else {
        unsigned short* vtp = C + 16777216;
        const int bb = (int)(mrow0 >> 10);
        const int ltok0 = (int)(mrow0 & 1023);
        #pragma unroll
        for (int rr = 0; rr < 8; ++rr) {
          const int nrow = rr * 8 + erow;
          s16x8 v = *(const s16x8*)(et + nrow * 72 + echunk * 8);
          *(s16x8*)(vtp + ((long)(bb * 1024 + nseg + nrow)) * 1024 + ltok0 + echunk * 8) = v;
        }
      }
    }
  }
}

// ---------------- flash attention ----------------
// 128 q rows per block (4 waves x 32), KV tile 64, defer-max (m=0) + lane-local l.
// q,k: [B*L][H] bf16 ; vt: [B*NH*HD][L] bf16 ; ctx: [B*L][H] bf16
__global__ __launch_bounds__(256) void flash_k(
    const unsigned short* __restrict__ q, const unsigned short* __restrict__ k,
    const unsigned short* __restrict__ vt, unsigned short* __restrict__ ctx)
{
  __shared__ unsigned short Ks[64 * 128];    // [kv][hd], rows 256B, chunk^=(row&7)
  __shared__ unsigned short Vs[128 * 64];    // [hd][kv], rows 128B, chunk^=(row&7)
  __shared__ unsigned short Ps[4][32 * 72];  // per-wave P [32 q][64 kv], pitch 72 (144B)
  const int qt = blockIdx.x, h = blockIdx.y, b = blockIdx.z;
  const int tid = threadIdx.x, lane = tid & 63, w = tid >> 6;
  const int rA = lane & 15, g = lane >> 4;
  const int q0w = qt * 128 + w * 32;         // wave's 32 q rows

  s16x8 qf[2][4];
  #pragma unroll
  for (int qi = 0; qi < 2; ++qi) {
    const unsigned short* qp = q + ((long)(b * Ln + q0w + qi * 16 + rA)) * Hn + h * HDn + g * 8;
    #pragma unroll
    for (int kk = 0; kk < 4; ++kk) qf[qi][kk] = *(const s16x8*)(qp + kk * 32);
  }

  f32x4 o[2][8];
  const f32x4 zero = {0.f, 0.f, 0.f, 0.f};
  #pragma unroll
  for (int qi = 0; qi < 2; ++qi)
    #pragma unroll
    for (int nn = 0; nn < 8; ++nn) o[qi][nn] = zero;
  float lrun[2][4];
  #pragma unroll
  for (int qi = 0; qi < 2; ++qi)
    #pragma unroll
    for (int j = 0; j < 4; ++j) lrun[qi][j] = 0.f;
  float m = 0.f;

  const float sc2 = 0.08838834764831845f * 1.4426950408889634f;  // 1/sqrt(128)*log2(e)

  const int krow0 = w * 16 + g;
  const int kc = lane & 15;
  const int vrow0 = w * 32 + (lane >> 3);
  const int vc = lane & 7;

  for (int kvt = 0; kvt < 16; ++kvt) {
    const int kv0 = kvt * 64;
    __syncthreads();
    #pragma unroll
    for (int qq = 0; qq < 4; ++qq) {
      const int rk = krow0 + qq * 4;
      gload16(k + ((long)(b * Ln + kv0 + rk)) * Hn + h * HDn + ((kc ^ (rk & 7)) * 8),
              (char*)Ks + w * 4096 + qq * 1024);
      const int rv = vrow0 + qq * 8;
      gload16(vt + ((long)(b * 1024 + h * HDn + rv)) * Ln + kv0 + ((vc ^ (rv & 7)) * 8),
              (char*)Vs + w * 4096 + qq * 1024);
    }
    __syncthreads();

    f32x4 sacc[2][4];
    #pragma unroll
    for (int qi = 0; qi < 2; ++qi)
      #pragma unroll
      for (int nj = 0; nj < 4; ++nj) sacc[qi][nj] = zero;
    #pragma unroll
    for (int kk = 0; kk < 4; ++kk) {
      #pragma unroll
      for (int nj = 0; nj < 4; ++nj) {
        const int row = nj * 16 + rA;
        const int byt = row * 256 + (((kk * 4 + g) ^ (row & 7)) << 4);
        s16x8 kf = *(const s16x8*)((const char*)Ks + byt);
        sacc[0][nj] = __builtin_amdgcn_mfma_f32_16x16x32_bf16(qf[0][kk], kf, sacc[0][nj], 0, 0, 0);
        sacc[1][nj] = __builtin_amdgcn_mfma_f32_16x16x32_bf16(qf[1][kk], kf, sacc[1][nj], 0, 0, 0);
      }
    }

    float vmax = -3.0e38f;
    #pragma unroll
    for (int qi = 0; qi < 2; ++qi)
      #pragma unroll
      for (int nj = 0; nj < 4; ++nj)
        #pragma unroll
        for (int j = 0; j < 4; ++j) {
          const float s = sacc[qi][nj][j] * sc2;
          sacc[qi][nj][j] = s;
          vmax = fmaxf(vmax, s);
        }
    if (!__all(vmax <= m + 8.0f)) {
      float mn = vmax;
      #pragma unroll
      for (int mm = 1; mm < 64; mm <<= 1) mn = fmaxf(mn, __shfl_xor(mn, mm, 64));
      const float al = exp2f(m - mn);
      #pragma unroll
      for (int qi = 0; qi < 2; ++qi) {
        #pragma unroll
        for (int nn = 0; nn < 8; ++nn)
          #pragma unroll
          for (int j = 0; j < 4; ++j) o[qi][nn][j] *= al;
        #pragma unroll
        for (int j = 0; j < 4; ++j) lrun[qi][j] *= al;
      }
      m = mn;
    }
    #pragma unroll
    for (int qi = 0; qi < 2; ++qi)
      #pragma unroll
      for (int j = 0; j < 4; ++j) {
        float p0 = exp2f(sacc[qi][0][j] - m);
        float p1 = exp2f(sacc[qi][1][j] - m);
        float p2 = exp2f(sacc[qi][2][j] - m);
        float p3 = exp2f(sacc[qi][3][j] - m);
        lrun[qi][j] += (p0 + p1) + (p2 + p3);
        const int prow = (qi * 16 + g * 4 + j) * 72;
        Ps[w][prow + 0 * 16 + rA] = f2bf(p0);
        Ps[w][prow + 1 * 16 + rA] = f2bf(p1);
        Ps[w][prow + 2 * 16 + rA] = f2bf(p2);
        Ps[w][prow + 3 * 16 + rA] = f2bf(p3);
      }

    s16x8 pf[2][2];
    #pragma unroll
    for (int qi = 0; qi < 2; ++qi)
      #pragma unroll
      for (int kk2 = 0; kk2 < 2; ++kk2)
        pf[qi][kk2] = *(const s16x8*)(&Ps[w][(qi * 16 + rA) * 72 + kk2 * 32 + g * 8]);
    #pragma unroll
    for (int kk2 = 0; kk2 < 2; ++kk2) {
      #pragma unroll
      for (int nn = 0; nn < 8; ++nn) {
        const int row = nn * 16 + rA;
        const int byt = row * 128 + (((kk2 * 4 + g) ^ (row & 7)) << 4);
        s16x8 vf = *(const s16x8*)((const char*)Vs + byt);
        o[0][nn] = __builtin_amdgcn_mfma_f32_16x16x32_bf16(pf[0][kk2], vf, o[0][nn], 0, 0, 0);
        o[1][nn] = __builtin_amdgcn_mfma_f32_16x16x32_bf16(pf[1][kk2], vf, o[1][nn], 0, 0, 0);
      }
    }
  }

  float linv[2][4];
  #pragma unroll
  for (int qi = 0; qi < 2; ++qi)
    #pragma unroll
    for (int j = 0; j < 4; ++j) {
      float l = lrun[qi][j];
      #pragma unroll
      for (int mm = 1; mm < 16; mm <<= 1) l += __shfl_xor(l, mm, 64);
      linv[qi][j] = 1.0f / l;
    }
  #pragma unroll
  for (int qi = 0; qi < 2; ++qi)
    #pragma unroll
    for (int nn = 0; nn < 8; ++nn)
      #pragma unroll
      for (int j = 0; j < 4; ++j) {
        const int row = q0w + qi * 16 + g * 4 + j;
        ctx[((long)(b * Ln + row)) * Hn + h * HDn + nn * 16 + rA] = f2bf(o[qi][nn][j] * linv[qi][j]);
      }
}

// ---------------- diversity ----------------
__global__ __launch_bounds__(256) void div_part_k(const unsigned short* __restrict__ br, float* __restrict__ part)
{
  const int b = blockIdx.y, ch = blockIdx.x;
  const unsigned short* a = br + (long)b * (2L * Sn * Hn);
  const unsigned short* c = a + (long)Sn * Hn;
  const int base = ch * 16384 + threadIdx.x * 8;
  float dot = 0.f, na = 0.f, nb = 0.f;
  #pragma unroll
  for (int i = 0; i < 8; ++i) {
    const int idx = base + i * 2048;
    s16x8 av = *(const s16x8*)(a + idx);
    s16x8 cv = *(const s16x8*)(c + idx);
    #pragma unroll
    for (int e = 0; e < 8; ++e) {
      float fa = bf2f((unsigned short)av[e]);
      float fc = bf2f((unsigned short)cv[e]);
      dot += fa * fc; na += fa * fa; nb += fc * fc;
    }
  }
  #pragma unroll
  for (int mm = 1; mm < 64; mm <<= 1) {
    dot += __shfl_xor(dot, mm, 64);
    na  += __shfl_xor(na, mm, 64);
    nb  += __shfl_xor(nb, mm, 64);
  }
  __shared__ float red[12];
  const int lane = threadIdx.x & 63, w = threadIdx.x >> 6;
  if (lane == 0) { red[w * 3] = dot; red[w * 3 + 1] = na; red[w * 3 + 2] = nb; }
  __syncthreads();
  if (threadIdx.x == 0) {
    float d = 0, x = 0, y = 0;
    for (int i = 0; i < 4; ++i) { d += red[i * 3]; x += red[i * 3 + 1]; y += red[i * 3 + 2]; }
    float* op = part + ((long)(b * 32 + ch)) * 3;
    op[0] = d; op[1] = x; op[2] = y;
  }
}

__global__ __launch_bounds__(64) void div_final_k(const float* __restrict__ part, float* __restrict__ outp)
{
  __shared__ float cosr[8];
  const int tid = threadIdx.x;
  if (tid < 8) {
    float d = 0, x = 0, y = 0;
    for (int i = 0; i < 32; ++i) {
      const float* p = part + ((long)(tid * 32 + i)) * 3;
      d += p[0]; x += p[1]; y += p[2];
    }
    cosr[tid] = d / fmaxf(sqrtf(x) * sqrtf(y), 1e-8f);
  }
  __syncthreads();
  if (tid == 0) {
    float s = 0.f;
    for (int i = 0; i < 8; ++i) s += 1.f - cosr[i];
    outp[0] = s * (1.f / 8.f);
  }
}

// ---------------- weighted combine ----------------
__global__ __launch_bounds__(256) void combine_k(const unsigned short* __restrict__ att,
                                                 const float* __restrict__ wts, float* __restrict__ out)
{
  const long i = ((long)blockIdx.x * 256 + threadIdx.x) * 8;
  const int b = (int)(i >> 19);           // S*H = 524288
  const long rem = i & 524287;
  const unsigned short* a0 = att + (long)b * (2L * Sn * Hn) + rem;
  const unsigned short* a1 = a0 + (long)Sn * Hn;
  const float w0 = wts[b * 2], w1 = wts[b * 2 + 1];
  s16x8 v0 = *(const s16x8*)a0;
  s16x8 v1 = *(const s16x8*)a1;
  float r[8];
  #pragma unroll
  for (int e = 0; e < 8; ++e) r[e] = w0 * bf2f((unsigned short)v0[e]) + w1 * bf2f((unsigned short)v1[e]);
  *(float4*)(out + i)     = make_float4(r[0], r[1], r[2], r[3]);
  *(float4*)(out + i + 4) = make_float4(r[4], r[5], r[6], r[7]);
}

// ---------------- launch ----------------
extern "C" void kernel_launch(void* const* d_in, const int* in_sizes, int n_in,
                              void* d_out, int out_size, void* d_ws, size_t ws_size,
                              hipStream_t stream)
{
  (void)in_sizes; (void)n_in; (void)out_size; (void)ws_size;
  const float* hidden   = (const float*)d_in[0];
  const float* router_w = (const float*)d_in[1];
  const float* router_b = (const float*)d_in[2];
  const float* W1 = (const float*)d_in[3];
  const float* b1 = (const float*)d_in[4];
  const float* W2 = (const float*)d_in[5];
  const float* b2 = (const float*)d_in[6];
  const float* Wq = (const float*)d_in[7];
  const float* bq = (const float*)d_in[8];
  const float* Wk = (const float*)d_in[9];
  const float* bk = (const float*)d_in[10];
  const float* Wv = (const float*)d_in[11];
  const float* bv = (const float*)d_in[12];
  const float* Wo = (const float*)d_in[13];
  const float* bo = (const float*)d_in[14];
  float* out = (float*)d_out;

  char* ws = (char*)d_ws;
  float* pooled  = (float*)(ws);                    // 32KB
  float* ppart   = (float*)(ws + 32768);            // 128KB
  float* probs   = (float*)(ws + 163840);
  int*   topi    = (int*)  (ws + 164096);
  float* wts     = (float*)(ws + 164352);
  int*   flags   = (int*)  (ws + 164608);
  float* dpart   = (float*)(ws + 164864);           // 3KB
  float* qkvbias = (float*)(ws + 167936);           // 12KB
  unsigned short* hid_bf = (unsigned short*)(ws + 262144);                           // 8.39MB
  unsigned short* Wt     = (unsigned short*)(ws + 262144 + 8388608);                 // 67.1MB: W1t -> W2t -> q/k/vt
  unsigned short* hbuf   = (unsigned short*)(ws + 262144 + 8388608 + 67108864);      // 67.1MB: h -> ctx/att
  unsigned short* br     = (unsigned short*)(ws + 262144 + 8388608 + 134217728);     // 16.8MB
  unsigned short* wqkvo  = (unsigned short*)(ws + 262144 + 8388608 + 134217728 + 16777216); // 8.4MB
  unsigned short* qb  = Wt;
  unsigned short* kbf = Wt + 8388608;
  unsigned short* vt  = Wt + 16777216;
  unsigned short* ctx = hbuf;
  unsigned short* att = hbuf + 8388608;
  unsigned short* wqt = wqkvo;
  unsigned short* wkt = wqkvo + 1048576;
  unsigned short* wvt = wqkvo + 2097152;
  unsigned short* wot = wqkvo + 3145728;

  // 1. router path
  pool_part_k<<<dim3(Bn, 4), 256, 0, stream>>>(hidden, ppart);
  pool_final_k<<<dim3(32), 256, 0, stream>>>(ppart, pooled);
  router_k<<<1, 256, 0, stream>>>(pooled, router_w, router_b, probs, topi, wts, flags, out + OUT_COMBINED);

  // 2. bf16 conversions / transposes
  cvt_k<<<4096, 256, 0, stream>>>(hidden, hid_bf);
  bias3_k<<<4, 256, 0, stream>>>(bq, bk, bv, qkvbias);
  transpose_k<<<dim3(64, 16, Tn), 256, 0, stream>>>(W1, Wt, Hn, FFn, (long)Hn * FFn, (long)FFn * Hn, flags);
  transpose_k<<<dim3(16, 16, 1), 256, 0, stream>>>(Wq, wqt, Hn, Hn, 0, 0, nullptr);
  transpose_k<<<dim3(16, 16, 1), 256, 0, stream>>>(Wk, wkt, Hn, Hn, 0, 0, nullptr);
  transpose_k<<<dim3(16, 16, 1), 256, 0, stream>>>(Wv, wvt, Hn, Hn, 0, 0, nullptr);
  transpose_k<<<dim3(16, 16, 1), 256, 0, stream>>>(Wo, wot, Hn, Hn, 0, 0, nullptr);

  // 3. FFN1 (gelu): grid (32,2,16) = 1024 blocks
  gemmT_k<1, 0><<<dim3(FFn / 128, Sn / 256, 16), 256, 0, stream>>>(
      hid_bf, Wt, b1, hbuf, FFn, Hn, topi, 2,
      (long)Sn * Hn, 0L, (long)FFn * Hn, FFn, (long)Sn * FFn);

  // 4. W2 transpose reuses Wt region (W1t dead)
  transpose_k<<<dim3(16, 64, Tn), 256, 0, stream>>>(W2, Wt, FFn, Hn, (long)FFn * Hn, (long)Hn * FFn, flags);

  // 5. FFN2: grid (8,2,16) = 256 blocks
  gemmT_k<0, 0><<<dim3(Hn / 128, Sn / 256, 16), 256, 0, stream>>>(
      hbuf, Wt, b2, br, Hn, FFn, topi, 2,
      0L, (long)Sn * FFn, (long)Hn * FFn, Hn, (long)Sn * Hn);

  // 6. diversity from branch_out
  div_part_k<<<dim3(32, Bn), 256, 0, stream>>>(br, dpart);
  div_final_k<<<1, 64, 0, stream>>>(dpart, out + OUT_COMBINED + 1);

  // 7. fused QKV projection: grid (24,32) = 768 blocks
  gemmT_k<0, 1><<<dim3(3072 / 128, (Bn * Ln) / 256, 1), 256, 0, stream>>>(
      br, wqkvo, qkvbias, qb, 3072, Hn, nullptr, 0, 0L, 0L, 0L, 0, 0L);

  // 8. flash attention (128 q rows/block)
  flash_k<<<dim3(Ln / 128, NHn, Bn), 256, 0, stream>>>(qb, kbf, vt, ctx);

  // 9. output projection: grid (8,32) = 256 blocks
  gemmT_k<0, 0><<<dim3(Hn / 128, (Bn * Ln) / 256, 1), 256, 0, stream>>>(
      ctx, wot, bo, att, Hn, Hn, nullptr, 0, 0L, 0L, 0L, 0, 0L);

  // 10. weighted combine -> f32 output
  combine_k<<<2048, 256, 0, stream>>>(att, wts, out);
}

// Round 6
// 517.739 us; speedup vs baseline: 1.2117x; 1.0120x over previous
//
#include <hip/hip_runtime.h>
#include <hip/hip_bf16.h>
#include <math.h>

typedef float f32x4 __attribute__((ext_vector_type(4)));
typedef short s16x8 __attribute__((ext_vector_type(8)));
typedef short s16x4 __attribute__((ext_vector_type(4)));
typedef unsigned int u32;

#define DEVI __device__ __forceinline__

// ---- sizes ----
#define Bn   8
#define Sn   512
#define Hn   1024
#define Tn   8
#define Kn   2
#define FFn  4096
#define NHn  8
#define HDn  128
#define Ln   1024            // K*S
#define OUT_COMBINED 4194304 // B*S*H

DEVI unsigned short f2bf(float x) {
  __hip_bfloat16 h = __float2bfloat16(x);
  union { __hip_bfloat16 h; unsigned short u; } cv; cv.h = h; return cv.u;
}
DEVI float bf2f(unsigned short u) {
  union { u32 i; float f; } cv; cv.i = ((u32)u) << 16; return cv.f;
}
// tanh-form GELU: |err| vs exact erf-GELU < 1e-3 (bf16 eps dominates)
DEVI float gelu_f(float x) {
  float t = x * x * x;
  float y = 0.7978845608028654f * x + 0.03567740813f * t;
  float e = exp2f(2.8853900817779268f * y);      // e^{2y}
  return x - x / (e + 1.0f);                      // x * e/(e+1)
}

typedef __attribute__((address_space(3))) u32 lds_u32;
typedef __attribute__((address_space(1))) u32 glb_u32;
DEVI void gload16(const void* g, void* l) {
  __builtin_amdgcn_global_load_lds((const glb_u32*)g, (lds_u32*)l, 16, 0, 0);
}

// ---------------- pool (mean over S) ----------------
__global__ __launch_bounds__(256) void pool_part_k(const float* __restrict__ hid, float* __restrict__ part)
{
  const int b = blockIdx.x, scn = blockIdx.y;
  const int hh = threadIdx.x * 4;
  float4 acc = make_float4(0.f, 0.f, 0.f, 0.f);
  const float* base = hid + ((long)b * Sn + (long)scn * 128) * Hn + hh;
  for (int s = 0; s < 128; ++s) {
    float4 v = *(const float4*)(base + (long)s * Hn);
    acc.x += v.x; acc.y += v.y; acc.z += v.z; acc.w += v.w;
  }
  *(float4*)(part + ((long)(scn * Bn + b)) * Hn + hh) = acc;
}

__global__ __launch_bounds__(256) void pool_final_k(const float* __restrict__ part, float* __restrict__ pooled)
{
  const int i = blockIdx.x * 256 + threadIdx.x;
  float s = 0.f;
  for (int sc = 0; sc < 4; ++sc) s += part[sc * (Bn * Hn) + i];
  pooled[i] = s * (1.f / (float)Sn);
}

// ---------------- router + entropy (parallel dot: 256 threads) ----------------
__global__ __launch_bounds__(256) void router_k(
    const float* __restrict__ pooled, const float* __restrict__ rw, const float* __restrict__ rb,
    float* __restrict__ probs, int* __restrict__ topi, float* __restrict__ wts,
    int* __restrict__ flags, float* __restrict__ entropy_out)
{
  __shared__ float partial[256];
  __shared__ float lg[64];
  __shared__ int sfl[8];
  __shared__ float sent[8];
  const int tid = threadIdx.x;
  const int bt = tid & 63, slice = tid >> 6;
  const int b = bt >> 3, t = bt & 7;
  if (tid < 8) sfl[tid] = 0;
  float acc = 0.f;
  const float* pb = pooled + b * Hn;
  for (int i = slice * 256; i < slice * 256 + 256; ++i) acc += pb[i] * rw[i * Tn + t];
  partial[tid] = acc;
  __syncthreads();
  if (tid < 64) lg[tid] = rb[t] + partial[tid] + partial[tid + 64] + partial[tid + 128] + partial[tid + 192];
  __syncthreads();
  if (tid < 64 && t == 0) {
    float p[8];
    float mx = lg[b * 8];
    for (int i = 1; i < 8; ++i) mx = fmaxf(mx, lg[b * 8 + i]);
    float ssum = 0.f;
    for (int i = 0; i < 8; ++i) { p[i] = expf(lg[b * 8 + i] - mx); ssum += p[i]; }
    float ent = 0.f;
    for (int i = 0; i < 8; ++i) { p[i] /= ssum; ent -= p[i] * logf(p[i] + 1e-8f); probs[b * 8 + i] = p[i]; }
    sent[b] = ent;
    int i1 = 0;
    for (int i = 1; i < 8; ++i) if (p[i] > p[i1]) i1 = i;   // strict > : lowest index on ties (lax.top_k)
    int i2 = (i1 == 0) ? 1 : 0;
    for (int i = 0; i < 8; ++i) if (i != i1 && p[i] > p[i2]) i2 = i;
    float w0 = 1.f / (1.f + expf(p[i2] - p[i1]));
    float w1 = 1.f / (1.f + expf(p[i1] - p[i2]));
    topi[b * 2] = i1; topi[b * 2 + 1] = i2;
    wts[b * 2] = w0; wts[b * 2 + 1] = w1;
    atomicOr(&sfl[i1], 1); atomicOr(&sfl[i2], 1);
  }
  __syncthreads();
  if (tid < 8) flags[tid] = sfl[tid];
  if (tid == 0) {
    float e = 0.f;
    for (int i = 0; i < 8; ++i) e += sent[i];
    entropy_out[0] = e * (1.f / (float)Bn);
  }
}

// ---------------- f32 -> bf16 convert ----------------
__global__ __launch_bounds__(256) void cvt_k(const float* __restrict__ in, unsigned short* __restrict__ out)
{
  const long i = ((long)blockIdx.x * 256 + threadIdx.x) * 4;
  float4 v = *(const float4*)(in + i);
  s16x4 o;
  o[0] = (short)f2bf(v.x); o[1] = (short)f2bf(v.y); o[2] = (short)f2bf(v.z); o[3] = (short)f2bf(v.w);
  *(s16x4*)(out + i) = o;
}

// ---------------- bias concat for fused QKV ----------------
__global__ __launch_bounds__(256) void bias3_k(const float* __restrict__ bq, const float* __restrict__ bk,
                                               const float* __restrict__ bv, float* __restrict__ o)
{
  const int i = blockIdx.x * 256 + threadIdx.x;   // 0..1023
  o[i] = bq[i]; o[i + 1024] = bk[i]; o[i + 2048] = bv[i];
}

// ---------------- transpose+convert: in f32 [Kd][N] -> out bf16 [N][Kd], 64x64 tiles ----------------
__global__ __launch_bounds__(256) void transpose_k(const float* __restrict__ Win, unsigned short* __restrict__ Wout,
                                                   int Kd, int N, long sIn, long sOut, const int* __restrict__ flags)
{
  const int t = blockIdx.z;
  if (flags && flags[t] == 0) return;   // uniform per block
  __shared__ float tile[64][65];
  const float* in = Win + (long)t * sIn;
  unsigned short* out = Wout + (long)t * sOut;
  const int kb = blockIdx.y * 64, nb = blockIdx.x * 64;
  const int tx = threadIdx.x & 15, ty = threadIdx.x >> 4;
  #pragma unroll
  for (int i = 0; i < 4; ++i) {
    const int r = ty + i * 16;
    float4 v = *(const float4*)(in + (long)(kb + r) * N + nb + tx * 4);
    tile[r][tx * 4 + 0] = v.x; tile[r][tx * 4 + 1] = v.y;
    tile[r][tx * 4 + 2] = v.z; tile[r][tx * 4 + 3] = v.w;
  }
  __syncthreads();
  #pragma unroll
  for (int i = 0; i < 4; ++i) {
    const int n = ty + i * 16;
    s16x4 o;
    #pragma unroll
    for (int j = 0; j < 4; ++j) o[j] = (short)f2bf(tile[tx * 4 + j][n]);
    *(s16x4*)(out + (long)(nb + n) * Kd + kb + tx * 4) = o;
  }
}

// ---------------- GEMM: C[M,N] = A[M,Kd] @ Bt[N,Kd]^T + bias ----------------
// BM=256, BN=128, BK=32. 4 waves (2M x 2N), wave tile 128x64. NBUF=3 (72KB LDS)
// -> 2 blocks/CU. SINGLE barrier per K-tile (mid-phase barriers removed: reads
// target cb, DMA writes target fb != cb -> no hazard; compiler's fine-grained
// lgkmcnt interleaves the 12 ds_reads under the 32 MFMAs; waves drift within
// the K-tile so LDS and MFMA pipes overlap both intra-block and across the
// 2 co-resident blocks).
// Boundary: s_waitcnt vmcnt(6) lgkmcnt(0) + s_barrier. vmcnt(6): 6 issues/
// wave/K-tile staged 2 ahead -> the 6 oldest (tile kt+1) landed. lgkmcnt(0):
// raw s_barrier doesn't drain LDS counters; closes in-flight-read vs
// next-tile-DMA-write race.
// Swizzle: chunk ^= (row&3)^((row>>2)&3) via pre-swizzled GLOBAL source.
// T1: bijective XCD remap. EPI 1 = tanh-GELU. OUTMODE 1 = fused QKV.
template<int EPI, int OUTMODE>
__global__ __launch_bounds__(256, 2) void gemmT_k(
    const unsigned short* __restrict__ A0, const unsigned short* __restrict__ Bt0,
    const float* __restrict__ bias0, unsigned short* __restrict__ C0,
    int N, int Kd,
    const int* __restrict__ topi, int kTop,
    long sA_b, long sA_p, long sBt_t, int sBias_t, long sC_p)
{
  __shared__ __align__(16) char smem[73728];
  char* const Ab = smem;              // 3 x 16384 (256 rows x 64B)
  char* const Bb = smem + 49152;      // 3 x  8192 (128 rows x 64B)

  // ---- T1 bijective XCD tile remap ----
  const int gx = gridDim.x, gy = gridDim.y;
  const int nwg = gx * gy * gridDim.z;
  const int hw = blockIdx.x + gx * (blockIdx.y + gy * blockIdx.z);
  const int q = nwg >> 3, r = nwg & 7;
  const int xcd = hw & 7, sub = hw >> 3;
  int lin = (xcd < r ? xcd * (q + 1) : r * (q + 1) + (xcd - r) * q) + sub;
  const int bx = lin % gx; lin /= gx;
  const int by = lin % gy;
  const int bz = lin / gy;

  const int bidx = kTop ? (bz / kTop) : 0;
  const int te = topi ? topi[bz] : 0;
  const unsigned short* A = A0 + (long)bidx * sA_b + (long)bz * sA_p;
  const unsigned short* Bt = Bt0 + (long)te * sBt_t;
  const float* bias = bias0 + (long)te * sBias_t;
  unsigned short* C = C0 + (long)bz * sC_p;

  const int m0 = by * 256;
  const int n0 = bx * 128;
  const int tid = threadIdx.x;
  const int lane = tid & 63, w = tid >> 6;
  const int wm = w >> 1, wn = w & 1;
  const int rA = lane & 15, g = lane >> 4;

  // ---- staging sources (pre-swizzled global chunk) ----
  const int sr = lane >> 2;                 // 0..15 (row within 16-row issue block)
  const int sc = lane & 3;                  // chunk
  const int csw = (sc ^ ((sr & 3) ^ ((sr >> 2) & 3))) * 8;   // bf16-elem offset
  const unsigned short* gAw = A + (long)(m0 + w * 64 + sr) * Kd + csw;  // + i*16*Kd + kt*32
  const unsigned short* gBw = Bt + (long)(n0 + w * 32 + sr) * Kd + csw;
  const int ldso = lane << 4;

  // ---- fragment LDS byte offsets (swizzled read) ----
  const int sl = (rA & 3) ^ ((rA >> 2) & 3);
  int aoff[8], boff[4];
  #pragma unroll
  for (int mi = 0; mi < 8; ++mi)
    aoff[mi] = (wm * 128 + mi * 16 + rA) * 64 + ((g ^ sl) << 4);
  #pragma unroll
  for (int nj = 0; nj < 4; ++nj)
    boff[nj] = (wn * 64 + nj * 16 + rA) * 64 + ((g ^ sl) << 4);

  f32x4 acc[8][4];
  const f32x4 zero = {0.f, 0.f, 0.f, 0.f};
  #pragma unroll
  for (int i = 0; i < 8; ++i)
    #pragma unroll
    for (int j = 0; j < 4; ++j) acc[i][j] = zero;

  const int nt = Kd >> 5;

  auto stageA = [&](int kt2, int buf, int i) {
    gload16(gAw + (long)i * 16 * Kd + kt2 * 32, Ab + buf * 16384 + w * 4096 + i * 1024 + ldso);
  };
  auto stageB = [&](int kt2, int buf, int i) {
    gload16(gBw + (long)i * 16 * Kd + kt2 * 32, Bb + buf * 8192 + w * 2048 + i * 1024 + ldso);
  };

  // ---- prologue: stage tiles 0,1 (6 issues each, in order) ----
  #pragma unroll
  for (int j = 0; j < 2; ++j) {
    stageA(j, j, 0); stageA(j, j, 1); stageB(j, j, 0);
    stageA(j, j, 2); stageA(j, j, 3); stageB(j, j, 1);
  }
  asm volatile("s_waitcnt vmcnt(6)" ::: "memory");   // tile 0 landed
  __builtin_amdgcn_s_barrier();

  int cb = 0, fb = 2;
  for (int kt = 0; kt < nt; ++kt) {
    const char* pa = Ab + cb * 16384;
    const char* pb = Bb + cb * 8192;
    const bool st = (kt + 2 < nt);
    const int ft = kt + 2;

    // ---- issue all 12 fragment reads + 6 stage issues; no mid barrier ----
    s16x8 af[8], bf[4];
    #pragma unroll
    for (int mi = 0; mi < 4; ++mi) af[mi] = *(const s16x8*)(pa + aoff[mi]);
    #pragma unroll
    for (int nj = 0; nj < 4; ++nj) bf[nj] = *(const s16x8*)(pb + boff[nj]);
    if (st) { stageA(ft, fb, 0); stageA(ft, fb, 1); stageB(ft, fb, 0); }
    #pragma unroll
    for (int mi = 0; mi < 4; ++mi) af[4 + mi] = *(const s16x8*)(pa + aoff[4 + mi]);
    if (st) { stageA(ft, fb, 2); stageA(ft, fb, 3); stageB(ft, fb, 1); }

    // ---- 32 MFMA (compiler lgkmcnt interleaves remaining reads underneath) ----
    __builtin_amdgcn_s_setprio(1);
    #pragma unroll
    for (int mi = 0; mi < 8; ++mi)
      #pragma unroll
      for (int nj = 0; nj < 4; ++nj)
        acc[mi][nj] = __builtin_amdgcn_mfma_f32_16x16x32_bf16(af[mi], bf[nj], acc[mi][nj], 0, 0, 0);
    __builtin_amdgcn_s_setprio(0);

    // ---- K-tile boundary: tile kt+1 resident + own reads drained ----
    if (st)                asm volatile("s_waitcnt vmcnt(6) lgkmcnt(0)" ::: "memory");
    else if (kt + 1 < nt)  asm volatile("s_waitcnt vmcnt(0) lgkmcnt(0)" ::: "memory");
    else                   asm volatile("s_waitcnt lgkmcnt(0)" ::: "memory");
    __builtin_amdgcn_s_barrier();
    cb = (cb + 1 == 3) ? 0 : cb + 1;
    fb = (fb + 1 == 3) ? 0 : fb + 1;
  }

  __syncthreads();   // drain before LDS reuse for epilogue

  // ---- epilogue via per-wave LDS tiles (two 64x64 parts, pitch 72 shorts) ----
  unsigned short* et = (unsigned short*)(smem + w * 9216);
  const int r4 = (lane >> 4) << 2;
  const int nbase = n0 + wn * 64;
  const int seg = (OUTMODE == 1) ? (nbase >> 10) : 0;
  const int erow = lane >> 3, echunk = lane & 7;
  float bv[4];
  #pragma unroll
  for (int nj = 0; nj < 4; ++nj) bv[nj] = bias[nbase + nj * 16 + rA];

  #pragma unroll
  for (int p = 0; p < 2; ++p) {
    #pragma unroll
    for (int nj = 0; nj < 4; ++nj) {
      #pragma unroll
      for (int mi2 = 0; mi2 < 4; ++mi2) {
        #pragma unroll
        for (int j = 0; j < 4; ++j) {
          float x = acc[p * 4 + mi2][nj][j] + bv[nj];
          if (EPI == 1) x = gelu_f(x);
          const int mrl = mi2 * 16 + r4 + j;
          const int ncl = nj * 16 + rA;
          if (OUTMODE == 0 || seg < 2) et[mrl * 72 + ncl] = f2bf(x);
          else                         et[ncl * 72 + mrl] = f2bf(x);
        }
      }
    }
    const long mrow0 = m0 + wm * 128 + p * 64;
    if (OUTMODE == 0) {
      #pragma unroll
      for (int rr = 0; rr < 8; ++rr) {
        const int row = rr * 8 + erow;
        s16x8 v = *(const s16x8*)(et + row * 72 + echunk * 8);
        *(s16x8*)(C + (mrow0 + row) * N + nbase + echunk * 8) = v;
      }
    } else {
      const int nseg = nbase & 1023;
      if (seg < 2) {
        unsigned short* dst = C + (long)seg * 8388608;
        #pragma unroll
        for (int rr = 0; rr < 8; ++rr) {
          const int row = rr * 8 + erow;
          s16x8 v = *(const s16x8*)(et + row * 72 + echunk * 8);
          *(s16x8*)(dst + (mrow0 + row) * 1024 + nseg + echunk * 8) = v;
        }
      } else {
        unsigned short* vtp = C + 16777216;
        const int bb = (int)(mrow0 >> 10);
        const int ltok0 = (int)(mrow0 & 1023);
        #pragma unroll
        for (int rr = 0; rr < 8; ++rr) {
          const int nrow = rr * 8 + erow;
          s16x8 v = *(const s16x8*)(et + nrow * 72 + echunk * 8);
          *(s16x8*)(vtp + ((long)(bb * 1024 + nseg + nrow)) * 1024 + ltok0 + echunk * 8) = v;
        }
      }
    }
  }
}

// ---------------- flash attention ----------------
// 128 q rows per block (4 waves x 32), KV tile 64, defer-max (m=0) + lane-local l.
// q,k: [B*L][H] bf16 ; vt: [B*NH*HD][L] bf16 ; ctx: [B*L][H] bf16
__global__ __launch_bounds__(256) void flash_k(
    const unsigned short* __restrict__ q, const unsigned short* __restrict__ k,
    const unsigned short* __restrict__ vt, unsigned short* __restrict__ ctx)
{
  __shared__ unsigned short Ks[64 * 128];    // [kv][hd], rows 256B, chunk^=(row&7)
  __shared__ unsigned short Vs[128 * 64];    // [hd][kv], rows 128B, chunk^=(row&7)
  __shared__ unsigned short Ps[4][32 * 72];  // per-wave P [32 q][64 kv], pitch 72 (144B)
  const int qt = blockIdx.x, h = blockIdx.y, b = blockIdx.z;
  const int tid = threadIdx.x, lane = tid & 63, w = tid >> 6;
  const int rA = lane & 15, g = lane >> 4;
  const int q0w = qt * 128 + w * 32;         // wave's 32 q rows

  s16x8 qf[2][4];
  #pragma unroll
  for (int qi = 0; qi < 2; ++qi) {
    const unsigned short* qp = q + ((long)(b * Ln + q0w + qi * 16 + rA)) * Hn + h * HDn + g * 8;
    #pragma unroll
    for (int kk = 0; kk < 4; ++kk) qf[qi][kk] = *(const s16x8*)(qp + kk * 32);
  }

  f32x4 o[2][8];
  const f32x4 zero = {0.f, 0.f, 0.f, 0.f};
  #pragma unroll
  for (int qi = 0; qi < 2; ++qi)
    #pragma unroll
    for (int nn = 0; nn < 8; ++nn) o[qi][nn] = zero;
  float lrun[2][4];
  #pragma unroll
  for (int qi = 0; qi < 2; ++qi)
    #pragma unroll
    for (int j = 0; j < 4; ++j) lrun[qi][j] = 0.f;
  float m = 0.f;

  const float sc2 = 0.08838834764831845f * 1.4426950408889634f;  // 1/sqrt(128)*log2(e)

  const int krow0 = w * 16 + g;
  const int kc = lane & 15;
  const int vrow0 = w * 32 + (lane >> 3);
  const int vc = lane & 7;

  for (int kvt = 0; kvt < 16; ++kvt) {
    const int kv0 = kvt * 64;
    __syncthreads();
    #pragma unroll
    for (int qq = 0; qq < 4; ++qq) {
      const int rk = krow0 + qq * 4;
      gload16(k + ((long)(b * Ln + kv0 + rk)) * Hn + h * HDn + ((kc ^ (rk & 7)) * 8),
              (char*)Ks + w * 4096 + qq * 1024);
      const int rv = vrow0 + qq * 8;
      gload16(vt + ((long)(b * 1024 + h * HDn + rv)) * Ln + kv0 + ((vc ^ (rv & 7)) * 8),
              (char*)Vs + w * 4096 + qq * 1024);
    }
    __syncthreads();

    f32x4 sacc[2][4];
    #pragma unroll
    for (int qi = 0; qi < 2; ++qi)
      #pragma unroll
      for (int nj = 0; nj < 4; ++nj) sacc[qi][nj] = zero;
    #pragma unroll
    for (int kk = 0; kk < 4; ++kk) {
      #pragma unroll
      for (int nj = 0; nj < 4; ++nj) {
        const int row = nj * 16 + rA;
        const int byt = row * 256 + (((kk * 4 + g) ^ (row & 7)) << 4);
        s16x8 kf = *(const s16x8*)((const char*)Ks + byt);
        sacc[0][nj] = __builtin_amdgcn_mfma_f32_16x16x32_bf16(qf[0][kk], kf, sacc[0][nj], 0, 0, 0);
        sacc[1][nj] = __builtin_amdgcn_mfma_f32_16x16x32_bf16(qf[1][kk], kf, sacc[1][nj], 0, 0, 0);
      }
    }

    float vmax = -3.0e38f;
    #pragma unroll
    for (int qi = 0; qi < 2; ++qi)
      #pragma unroll
      for (int nj = 0; nj < 4; ++nj)
        #pragma unroll
        for (int j = 0; j < 4; ++j) {
          const float s = sacc[qi][nj][j] * sc2;
          sacc[qi][nj][j] = s;
          vmax = fmaxf(vmax, s);
        }
    if (!__all(vmax <= m + 8.0f)) {
      float mn = vmax;
      #pragma unroll
      for (int mm = 1; mm < 64; mm <<= 1) mn = fmaxf(mn, __shfl_xor(mn, mm, 64));
      const float al = exp2f(m - mn);
      #pragma unroll
      for (int qi = 0; qi < 2; ++qi) {
        #pragma unroll
        for (int nn = 0; nn < 8; ++nn)
          #pragma unroll
          for (int j = 0; j < 4; ++j) o[qi][nn][j] *= al;
        #pragma unroll
        for (int j = 0; j < 4; ++j) lrun[qi][j] *= al;
      }
      m = mn;
    }
    #pragma unroll
    for (int qi = 0; qi < 2; ++qi)
      #pragma unroll
      for (int j = 0; j < 4; ++j) {
        float p0 = exp2f(sacc[qi][0][j] - m);
        float p1 = exp2f(sacc[qi][1][j] - m);
        float p2 = exp2f(sacc[qi][2][j] - m);
        float p3 = exp2f(sacc[qi][3][j] - m);
        lrun[qi][j] += (p0 + p1) + (p2 + p3);
        const int prow = (qi * 16 + g * 4 + j) * 72;
        Ps[w][prow + 0 * 16 + rA] = f2bf(p0);
        Ps[w][prow + 1 * 16 + rA] = f2bf(p1);
        Ps[w][prow + 2 * 16 + rA] = f2bf(p2);
        Ps[w][prow + 3 * 16 + rA] = f2bf(p3);
      }

    s16x8 pf[2][2];
    #pragma unroll
    for (int qi = 0; qi < 2; ++qi)
      #pragma unroll
      for (int kk2 = 0; kk2 < 2; ++kk2)
        pf[qi][kk2] = *(const s16x8*)(&Ps[w][(qi * 16 + rA) * 72 + kk2 * 32 + g * 8]);
    #pragma unroll
    for (int kk2 = 0; kk2 < 2; ++kk2) {
      #pragma unroll
      for (int nn = 0; nn < 8; ++nn) {
        const int row = nn * 16 + rA;
        const int byt = row * 128 + (((kk2 * 4 + g) ^ (row & 7)) << 4);
        s16x8 vf = *(const s16x8*)((const char*)Vs + byt);
        o[0][nn] = __builtin_amdgcn_mfma_f32_16x16x32_bf16(pf[0][kk2], vf, o[0][nn], 0, 0, 0);
        o[1][nn] = __builtin_amdgcn_mfma_f32_16x16x32_bf16(pf[1][kk2], vf, o[1][nn], 0, 0, 0);
      }
    }
  }

  float linv[2][4];
  #pragma unroll
  for (int qi = 0; qi < 2; ++qi)
    #pragma unroll
    for (int j = 0; j < 4; ++j) {
      float l = lrun[qi][j];
      #pragma unroll
      for (int mm = 1; mm < 16; mm <<= 1) l += __shfl_xor(l, mm, 64);
      linv[qi][j] = 1.0f / l;
    }
  #pragma unroll
  for (int qi = 0; qi < 2; ++qi)
    #pragma unroll
    for (int nn = 0; nn < 8; ++nn)
      #pragma unroll
      for (int j = 0; j < 4; ++j) {
        const int row = q0w + qi * 16 + g * 4 + j;
        ctx[((long)(b * Ln + row)) * Hn + h * HDn + nn * 16 + rA] = f2bf(o[qi][nn][j] * linv[qi][j]);
      }
}

// ---------------- diversity ----------------
__global__ __launch_bounds__(256) void div_part_k(const unsigned short* __restrict__ br, float* __restrict__ part)
{
  const int b = blockIdx.y, ch = blockIdx.x;
  const unsigned short* a = br + (long)b * (2L * Sn * Hn);
  const unsigned short* c = a + (long)Sn * Hn;
  const int base = ch * 16384 + threadIdx.x * 8;
  float dot = 0.f, na = 0.f, nb = 0.f;
  #pragma unroll
  for (int i = 0; i < 8; ++i) {
    const int idx = base + i * 2048;
    s16x8 av = *(const s16x8*)(a + idx);
    s16x8 cv = *(const s16x8*)(c + idx);
    #pragma unroll
    for (int e = 0; e < 8; ++e) {
      float fa = bf2f((unsigned short)av[e]);
      float fc = bf2f((unsigned short)cv[e]);
      dot += fa * fc; na += fa * fa; nb += fc * fc;
    }
  }
  #pragma unroll
  for (int mm = 1; mm < 64; mm <<= 1) {
    dot += __shfl_xor(dot, mm, 64);
    na  += __shfl_xor(na, mm, 64);
    nb  += __shfl_xor(nb, mm, 64);
  }
  __shared__ float red[12];
  const int lane = threadIdx.x & 63, w = threadIdx.x >> 6;
  if (lane == 0) { red[w * 3] = dot; red[w * 3 + 1] = na; red[w * 3 + 2] = nb; }
  __syncthreads();
  if (threadIdx.x == 0) {
    float d = 0, x = 0, y = 0;
    for (int i = 0; i < 4; ++i) { d += red[i * 3]; x += red[i * 3 + 1]; y += red[i * 3 + 2]; }
    float* op = part + ((long)(b * 32 + ch)) * 3;
    op[0] = d; op[1] = x; op[2] = y;
  }
}

__global__ __launch_bounds__(64) void div_final_k(const float* __restrict__ part, float* __restrict__ outp)
{
  __shared__ float cosr[8];
  const int tid = threadIdx.x;
  if (tid < 8) {
    float d = 0, x = 0, y = 0;
    for (int i = 0; i < 32; ++i) {
      const float* p = part + ((long)(tid * 32 + i)) * 3;
      d += p[0]; x += p[1]; y += p[2];
    }
    cosr[tid] = d / fmaxf(sqrtf(x) * sqrtf(y), 1e-8f);
  }
  __syncthreads();
  if (tid == 0) {
    float s = 0.f;
    for (int i = 0; i < 8; ++i) s += 1.f - cosr[i];
    outp[0] = s * (1.f / 8.f);
  }
}

// ---------------- weighted combine ----------------
__global__ __launch_bounds__(256) void combine_k(const unsigned short* __restrict__ att,
                                                 const float* __restrict__ wts, float* __restrict__ out)
{
  const long i = ((long)blockIdx.x * 256 + threadIdx.x) * 8;
  const int b = (int)(i >> 19);           // S*H = 524288
  const long rem = i & 524287;
  const unsigned short* a0 = att + (long)b * (2L * Sn * Hn) + rem;
  const unsigned short* a1 = a0 + (long)Sn * Hn;
  const float w0 = wts[b * 2], w1 = wts[b * 2 + 1];
  s16x8 v0 = *(const s16x8*)a0;
  s16x8 v1 = *(const s16x8*)a1;
  float r[8];
  #pragma unroll
  for (int e = 0; e < 8; ++e) r[e] = w0 * bf2f((unsigned short)v0[e]) + w1 * bf2f((unsigned short)v1[e]);
  *(float4*)(out + i)     = make_float4(r[0], r[1], r[2], r[3]);
  *(float4*)(out + i + 4) = make_float4(r[4], r[5], r[6], r[7]);
}

// ---------------- launch ----------------
extern "C" void kernel_launch(void* const* d_in, const int* in_sizes, int n_in,
                              void* d_out, int out_size, void* d_ws, size_t ws_size,
                              hipStream_t stream)
{
  (void)in_sizes; (void)n_in; (void)out_size; (void)ws_size;
  const float* hidden   = (const float*)d_in[0];
  const float* router_w = (const float*)d_in[1];
  const float* router_b = (const float*)d_in[2];
  const float* W1 = (const float*)d_in[3];
  const float* b1 = (const float*)d_in[4];
  const float* W2 = (const float*)d_in[5];
  const float* b2 = (const float*)d_in[6];
  const float* Wq = (const float*)d_in[7];
  const float* bq = (const float*)d_in[8];
  const float* Wk = (const float*)d_in[9];
  const float* bk = (const float*)d_in[10];
  const float* Wv = (const float*)d_in[11];
  const float* bv = (const float*)d_in[12];
  const float* Wo = (const float*)d_in[13];
  const float* bo = (const float*)d_in[14];
  float* out = (float*)d_out;

  char* ws = (char*)d_ws;
  float* pooled  = (float*)(ws);                    // 32KB
  float* ppart   = (float*)(ws + 32768);            // 128KB
  float* probs   = (float*)(ws + 163840);
  int*   topi    = (int*)  (ws + 164096);
  float* wts     = (float*)(ws + 164352);
  int*   flags   = (int*)  (ws + 164608);
  float* dpart   = (float*)(ws + 164864);           // 3KB
  float* qkvbias = (float*)(ws + 167936);           // 12KB
  unsigned short* hid_bf = (unsigned short*)(ws + 262144);                           // 8.39MB
  unsigned short* Wt     = (unsigned short*)(ws + 262144 + 8388608);                 // 67.1MB: W1t -> W2t -> q/k/vt
  unsigned short* hbuf   = (unsigned short*)(ws + 262144 + 8388608 + 67108864);      // 67.1MB: h -> ctx/att
  unsigned short* br     = (unsigned short*)(ws + 262144 + 8388608 + 134217728);     // 16.8MB
  unsigned short* wqkvo  = (unsigned short*)(ws + 262144 + 8388608 + 134217728 + 16777216); // 8.4MB
  unsigned short* qb  = Wt;
  unsigned short* kbf = Wt + 8388608;
  unsigned short* vt  = Wt + 16777216;
  unsigned short* ctx = hbuf;
  unsigned short* att = hbuf + 8388608;
  unsigned short* wqt = wqkvo;
  unsigned short* wkt = wqkvo + 1048576;
  unsigned short* wvt = wqkvo + 2097152;
  unsigned short* wot = wqkvo + 3145728;

  // 1. router path
  pool_part_k<<<dim3(Bn, 4), 256, 0, stream>>>(hidden, ppart);
  pool_final_k<<<dim3(32), 256, 0, stream>>>(ppart, pooled);
  router_k<<<1, 256, 0, stream>>>(pooled, router_w, router_b, probs, topi, wts, flags, out + OUT_COMBINED);

  // 2. bf16 conversions / transposes
  cvt_k<<<4096, 256, 0, stream>>>(hidden, hid_bf);
  bias3_k<<<4, 256, 0, stream>>>(bq, bk, bv, qkvbias);
  transpose_k<<<dim3(64, 16, Tn), 256, 0, stream>>>(W1, Wt, Hn, FFn, (long)Hn * FFn, (long)FFn * Hn, flags);
  transpose_k<<<dim3(16, 16, 1), 256, 0, stream>>>(Wq, wqt, Hn, Hn, 0, 0, nullptr);
  transpose_k<<<dim3(16, 16, 1), 256, 0, stream>>>(Wk, wkt, Hn, Hn, 0, 0, nullptr);
  transpose_k<<<dim3(16, 16, 1), 256, 0, stream>>>(Wv, wvt, Hn, Hn, 0, 0, nullptr);
  transpose_k<<<dim3(16, 16, 1), 256, 0, stream>>>(Wo, wot, Hn, Hn, 0, 0, nullptr);

  // 3. FFN1 (gelu): grid (32,2,16) = 1024 blocks
  gemmT_k<1, 0><<<dim3(FFn / 128, Sn / 256, 16), 256, 0, stream>>>(
      hid_bf, Wt, b1, hbuf, FFn, Hn, topi, 2,
      (long)Sn * Hn, 0L, (long)FFn * Hn, FFn, (long)Sn * FFn);

  // 4. W2 transpose reuses Wt region (W1t dead)
  transpose_k<<<dim3(16, 64, Tn), 256, 0, stream>>>(W2, Wt, FFn, Hn, (long)FFn * Hn, (long)Hn * FFn, flags);

  // 5. FFN2: grid (8,2,16) = 256 blocks
  gemmT_k<0, 0><<<dim3(Hn / 128, Sn / 256, 16), 256, 0, stream>>>(
      hbuf, Wt, b2, br, Hn, FFn, topi, 2,
      0L, (long)Sn * FFn, (long)Hn * FFn, Hn, (long)Sn * Hn);

  // 6. diversity from branch_out
  div_part_k<<<dim3(32, Bn), 256, 0, stream>>>(br, dpart);
  div_final_k<<<1, 64, 0, stream>>>(dpart, out + OUT_COMBINED + 1);

  // 7. fused QKV projection: grid (24,32) = 768 blocks
  gemmT_k<0, 1><<<dim3(3072 / 128, (Bn * Ln) / 256, 1), 256, 0, stream>>>(
      br, wqkvo, qkvbias, qb, 3072, Hn, nullptr, 0, 0L, 0L, 0L, 0, 0L);

  // 8. flash attention (128 q rows/block)
  flash_k<<<dim3(Ln / 128, NHn, Bn), 256, 0, stream>>>(qb, kbf, vt, ctx);

  // 9. output projection: grid (8,32) = 256 blocks
  gemmT_k<0, 0><<<dim3(Hn / 128, (Bn * Ln) / 256, 1), 256, 0, stream>>>(
      ctx, wot, bo, att, Hn, Hn, nullptr, 0, 0L, 0L, 0L, 0, 0L);

  // 10. weighted combine -> f32 output
  combine_k<<<2048, 256, 0, stream>>>(att, wts, out);
}